// Round 13
// baseline (1211.288 us; speedup 1.0000x reference)
//
#include <hip/hip_runtime.h>
#include <math.h>

#define NGNN   32768
#define NMAXD  1024
#define HIDD   128
#define CLSD   64
#define DDIM   192
#define ATTH   128
#define NEDGE  200000
#define NEOUT  500000
#define NSUB   1024
#define KMIX   20

#define NREP      64
#define LOSS_OFF  0
#define ALPHA_OFF 20480
#define CNT_OFF   40960
#define REP_STRIDE 41984

typedef __attribute__((ext_vector_type(8))) short bf16x8;
typedef __attribute__((ext_vector_type(8))) unsigned short u16x8;
typedef __attribute__((ext_vector_type(4))) float f32x4;

__device__ __forceinline__ float sigm(float x) { return 1.0f / (1.0f + __expf(-x)); }
__device__ __forceinline__ float tanhf_(float x) { return 2.0f / (1.0f + __expf(-2.0f * x)) - 1.0f; }

__device__ __forceinline__ short f2bf(float f) {
  union { float f; unsigned u; } v; v.f = f;
  unsigned r = v.u + 0x7FFFu + ((v.u >> 16) & 1u);
  return (short)(r >> 16);
}
__device__ __forceinline__ float bf2f(unsigned short u) {
  union { unsigned u; float f; } v; v.u = ((unsigned)u) << 16;
  return v.f;
}
__device__ __forceinline__ f32x4 bc4(float b) {
  f32x4 v; v[0] = b; v[1] = b; v[2] = b; v[3] = b; return v;
}
// bank swizzle on 16B-unit index (bijective involution)
__device__ __forceinline__ int swz(int u) { return u ^ ((u >> 4) & 7); }

// ---------------- CSR build (once): histogram by dst, scan, scatter
__global__ __launch_bounds__(256) void k_hist(const int* __restrict__ edges,
                                              int* __restrict__ deg) {
  const int e = blockIdx.x * 256 + threadIdx.x;
  if (e < NEDGE) atomicAdd(&deg[edges[2 * e + 1]], 1);
}

__global__ __launch_bounds__(1024) void k_scan(const int* deg_in,
                                               int* rowptr, int* cursor) {
  __shared__ int part[1024];
  const int t = threadIdx.x;
  const int base = t * 32;
  int loc[32];
  int s = 0;
#pragma unroll
  for (int i = 0; i < 32; i++) { loc[i] = deg_in[base + i]; s += loc[i]; }
  part[t] = s;
  __syncthreads();
  for (int off = 1; off < 1024; off <<= 1) {
    int v = 0;
    if (t >= off) v = part[t - off];
    __syncthreads();
    part[t] += v;
    __syncthreads();
  }
  int pre = (t == 0) ? 0 : part[t - 1];
#pragma unroll
  for (int i = 0; i < 32; i++) {
    rowptr[base + i] = pre;
    cursor[base + i] = pre;
    pre += loc[i];
  }
  if (t == 1023) rowptr[NGNN] = pre;
}

__global__ __launch_bounds__(256) void k_scatter(const int* __restrict__ edges,
                                                 int* __restrict__ cursor,
                                                 int* __restrict__ eidx) {
  const int e = blockIdx.x * 256 + threadIdx.x;
  if (e < NEDGE) {
    const int p = atomicAdd(&cursor[edges[2 * e + 1]], 1);
    eidx[p] = e;
  }
}

// ---------------- pack fp32 [K][N] weight into bf16 MFMA B-fragment order
__global__ __launch_bounds__(64) void k_pack(const float* __restrict__ W,
                                             short* __restrict__ out, int N, int CT) {
  const int l = threadIdx.x;
  const int ks = blockIdx.x / CT;
  const int ct = blockIdx.x % CT;
  const int row0 = ks * 32 + (l >> 4) * 8;
  const int col = ct * 16 + (l & 15);
  short v[8];
#pragma unroll
  for (int j = 0; j < 8; j++) {
    const float f = (col < N) ? W[(size_t)(row0 + j) * N + col] : 0.0f;
    v[j] = f2bf(f);
  }
  *(bf16x8*)(out + ((size_t)blockIdx.x * 64 + l) * 8) = *(bf16x8*)v;
}

// ---------------- nf = A @ W_dec + b_dec, exploiting A in {0,1} with ~5% density
__global__ __launch_bounds__(128) void k_dec(
    const float* __restrict__ A, const float* __restrict__ Wd,
    const float* __restrict__ bd, float* __restrict__ nf) {
  __shared__ float arow[NMAXD];
  __shared__ int   nz[NMAXD];
  __shared__ int   cnt;
  const int row = blockIdx.x;
  const int t = threadIdx.x;
  if (t == 0) cnt = 0;
  const float4* A4 = (const float4*)(A + (size_t)row * NMAXD);
  float4* a4 = (float4*)arow;
  a4[t] = A4[t];
  a4[t + 128] = A4[t + 128];
  __syncthreads();
  for (int i = t; i < NMAXD; i += 128) {
    if (arow[i] != 0.0f) {
      int p = atomicAdd(&cnt, 1);
      nz[p] = i;
    }
  }
  __syncthreads();
  float acc = bd[t];
  const int n = cnt;
  for (int i = 0; i < n; i++) acc += Wd[(size_t)nz[i] * HIDD + t];
  nf[(size_t)row * HIDD + t] = acc;
}

// ---------------- stbf[i] = bf16(concat(nf[nif[i]] (0-row aware), class_emb[cl[i]]))
__global__ __launch_bounds__(192) void k_state(
    const float* __restrict__ nf, const float* __restrict__ cemb,
    const int* __restrict__ nif, const int* __restrict__ cl,
    unsigned short* __restrict__ stbf) {
  const int i = blockIdx.x;
  const int t = threadIdx.x;
  float v;
  if (t < HIDD) {
    const int idx = nif[i];
    v = (idx == 0) ? 0.0f : nf[(size_t)(idx - 1) * HIDD + t];
  } else {
    v = cemb[cl[i] * CLSD + (t - HIDD)];
  }
  stbf[(size_t)i * DDIM + t] = (unsigned short)f2bf(v);
}

// ---------------- MFMA edge kernel v6: 32 edges/block, 256 threads (4 waves),
// LDS 32KB -> 5 blocks/CU. Outer-product column-split, K=320 in-register one-hot.
__global__ __launch_bounds__(256, 5) void k_edge_mfma(
    const unsigned short* __restrict__ stbf, const int* __restrict__ edges,
    const int* __restrict__ attidx,
    const float* __restrict__ bm1,
    const short* __restrict__ pWm1, const short* __restrict__ pWm2,
    const float* __restrict__ bm2,
    const float* __restrict__ ba1,
    const short* __restrict__ pWa1, const short* __restrict__ pWa2,
    const float* __restrict__ ba2,
    unsigned short* __restrict__ msgbuf) {
  __shared__ short pdiff[6144];  // [rt<2][ks<6][64][8] 12KB; later msgrow[32][192]
  __shared__ short phm[6144];    // hm A-frags (K=192)  12KB
  __shared__ short pha[4096];    // ha A-frags (K=128)   8KB
  const int t = threadIdx.x;
  const int e0 = blockIdx.x * 32;
  const int wid = t >> 6, l = t & 63;
  const int col16 = l & 15, rr = (l >> 4) * 4;
  const int cb = (l >> 4) * 8;

  // stage diff A-frags (swizzled): 768 tasks = 32 rows x 24 col-groups
  for (int it = 0; it < 3; it++) {
    const int id = t + 256 * it;
    const int r = id / 24, g24 = id % 24;
    const int e = e0 + r;
    const int s = edges[2 * e], d = edges[2 * e + 1];
    const u16x8 a = *(const u16x8*)&stbf[(size_t)s * DDIM + g24 * 8];
    const u16x8 b = *(const u16x8*)&stbf[(size_t)d * DDIM + g24 * 8];
    short v[8];
#pragma unroll
    for (int j = 0; j < 8; j++) v[j] = f2bf(bf2f(a[j]) - bf2f(b[j]));
    const int rt = r >> 4, ks = g24 >> 2, g = g24 & 3;
    *(bf16x8*)&pdiff[swz((rt * 6 + ks) * 64 + g * 16 + (r & 15)) * 8] = *(bf16x8*)v;
  }

  // per-lane one-hot targets for row (l&15) of each row-tile (direct global)
  int a0v[2], a1v[2];
#pragma unroll
  for (int rt = 0; rt < 2; rt++) {
    const int e = e0 + rt * 16 + (l & 15);
    a0v[rt] = attidx[edges[2 * e]] + 192;
    a1v[rt] = attidx[edges[2 * e + 1]] + 256;
  }
  __syncthreads();

  const int w5 = wid * 5;

  // ---- L1: [32x320] @ [320x(192|128)] fused, ks-outer outer-product ----
  {
    f32x4 acc[5][2];
#pragma unroll
    for (int u = 0; u < 5; u++)
#pragma unroll
      for (int rt = 0; rt < 2; rt++) acc[u][rt] = bc4(0.0f);

    for (int ks = 0; ks < 10; ks++) {
      bf16x8 A[2];
      if (ks < 6) {
#pragma unroll
        for (int rt = 0; rt < 2; rt++)
          A[rt] = *(const bf16x8*)&pdiff[swz((rt * 6 + ks) * 64 + l) * 8];
      } else {
        const int kb = ks * 32 + cb;
#pragma unroll
        for (int rt = 0; rt < 2; rt++) {
          short v[8];
#pragma unroll
          for (int j = 0; j < 8; j++) {
            const int kg = kb + j;
            v[j] = (kg == a0v[rt] || kg == a1v[rt]) ? (short)0x3F80 : (short)0;
          }
          A[rt] = *(bf16x8*)v;
        }
      }
      bf16x8 B[5];
#pragma unroll
      for (int u = 0; u < 5; u++) {
        const int unit = w5 + u;
        const short* bp = (unit < 12)
            ? &pWm1[((ks * 12 + unit) * 64 + l) * 8]
            : &pWa1[((ks * 8 + (unit - 12)) * 64 + l) * 8];
        B[u] = *(const bf16x8*)bp;
      }
#pragma unroll
      for (int u = 0; u < 5; u++)
#pragma unroll
        for (int rt = 0; rt < 2; rt++)
          acc[u][rt] = __builtin_amdgcn_mfma_f32_16x16x32_bf16(A[rt], B[u], acc[u][rt], 0, 0, 0);
    }

    // bias + relu + relayout to phm/pha (swizzled)
#pragma unroll
    for (int u = 0; u < 5; u++) {
      const int unit = w5 + u;
      const int isMsg = (unit < 12);
      const int ct = isMsg ? unit : unit - 12;
      const int col = ct * 16 + col16;
      const float bb = isMsg ? bm1[col] : ba1[col];
      const int ksp = col >> 5, gp = (col & 31) >> 3, jp = col & 7;
#pragma unroll
      for (int rt = 0; rt < 2; rt++)
#pragma unroll
        for (int j = 0; j < 4; j++) {
          const short hv = f2bf(fmaxf(acc[u][rt][j] + bb, 0.0f));
          if (isMsg) phm[swz((rt * 6 + ksp) * 64 + gp * 16 + rr + j) * 8 + jp] = hv;
          else       pha[swz((rt * 4 + ksp) * 64 + gp * 16 + rr + j) * 8 + jp] = hv;
        }
    }
  }
  __syncthreads();

  // ---- L2: wave owns 3 of 12 output cts x 2 rts ----
  {
    const int w3 = wid * 3;
    f32x4 m[3][2], av[3][2];
#pragma unroll
    for (int c = 0; c < 3; c++) {
      const int col = (w3 + c) * 16 + col16;
      const f32x4 bm = bc4(bm2[col]), ba = bc4(ba2[col]);
#pragma unroll
      for (int rt = 0; rt < 2; rt++) { m[c][rt] = bm; av[c][rt] = ba; }
    }
    for (int ks = 0; ks < 6; ks++) {
      bf16x8 A[2];
#pragma unroll
      for (int rt = 0; rt < 2; rt++)
        A[rt] = *(const bf16x8*)&phm[swz((rt * 6 + ks) * 64 + l) * 8];
      bf16x8 B[3];
#pragma unroll
      for (int c = 0; c < 3; c++)
        B[c] = *(const bf16x8*)&pWm2[((ks * 12 + w3 + c) * 64 + l) * 8];
#pragma unroll
      for (int c = 0; c < 3; c++)
#pragma unroll
        for (int rt = 0; rt < 2; rt++)
          m[c][rt] = __builtin_amdgcn_mfma_f32_16x16x32_bf16(A[rt], B[c], m[c][rt], 0, 0, 0);
    }
    for (int ks = 0; ks < 4; ks++) {
      bf16x8 A[2];
#pragma unroll
      for (int rt = 0; rt < 2; rt++)
        A[rt] = *(const bf16x8*)&pha[swz((rt * 4 + ks) * 64 + l) * 8];
      bf16x8 B[3];
#pragma unroll
      for (int c = 0; c < 3; c++)
        B[c] = *(const bf16x8*)&pWa2[((ks * 12 + w3 + c) * 64 + l) * 8];
#pragma unroll
      for (int c = 0; c < 3; c++)
#pragma unroll
        for (int rt = 0; rt < 2; rt++)
          av[c][rt] = __builtin_amdgcn_mfma_f32_16x16x32_bf16(A[rt], B[c], av[c][rt], 0, 0, 0);
    }

    // write combined values to LDS msgrow (overlays pdiff; dead since L1 + barrier)
    short* msgrow = pdiff;
#pragma unroll
    for (int c = 0; c < 3; c++) {
      const int col = (w3 + c) * 16 + col16;
#pragma unroll
      for (int rt = 0; rt < 2; rt++)
#pragma unroll
        for (int j = 0; j < 4; j++) {
          const int row = rt * 16 + rr + j;
          msgrow[swz(row * 24 + (col >> 3)) * 8 + (col & 7)] =
              f2bf(m[c][rt][j] * sigm(av[c][rt][j]));
        }
    }
  }
  __syncthreads();

  // coalesced copy msgrow -> msgbuf (32 rows x 384B)
  {
    const short* msgrow = pdiff;
    for (int it = 0; it < 3; it++) {
      const int id = t + 256 * it;      // 768 tasks
      const int r = id / 24, g = id % 24;
      *(float4*)&msgbuf[(size_t)(e0 + r) * DDIM + g * 8] =
          *(const float4*)&msgrow[swz(r * 24 + g) * 8];
    }
  }
}

// ---------------- MFMA GRU: 64 nodes/block, 256 threads (4 waves), zero LDS.
__global__ __launch_bounds__(256, 2) void k_gru_mfma(
    unsigned short* __restrict__ stbf,
    const unsigned short* __restrict__ msgbuf,
    const int* __restrict__ rowptr, const int* __restrict__ eidx,
    const short* __restrict__ pWih, const float* __restrict__ bih,
    const short* __restrict__ pWhh, const float* __restrict__ bhh) {
  const int t = threadIdx.x;
  const int n0 = blockIdx.x * 64;
  const int wid = t >> 6, l = t & 63;
  const int col16 = l & 15, rr = (l >> 4) * 4;
  const int cb = (l >> 4) * 8;
  const int row = n0 + wid * 16 + (l & 15);

  float afacc[6][8];
#pragma unroll
  for (int ks = 0; ks < 6; ks++)
#pragma unroll
    for (int j = 0; j < 8; j++) afacc[ks][j] = 0.0f;

  const int rbeg = rowptr[row], rend = rowptr[row + 1];
  for (int p = rbeg; p < rend; p++) {
    const int e = eidx[p];
    const unsigned short* mr = &msgbuf[(size_t)e * DDIM + cb];
#pragma unroll
    for (int ks = 0; ks < 6; ks++) {
      const u16x8 cc = *(const u16x8*)(mr + ks * 32);
#pragma unroll
      for (int j = 0; j < 8; j++) afacc[ks][j] += bf2f(cc[j]);
    }
  }

  bf16x8 af[6], sf[6];
#pragma unroll
  for (int ks = 0; ks < 6; ks++) {
    short v[8];
#pragma unroll
    for (int j = 0; j < 8; j++) v[j] = f2bf(afacc[ks][j]);
    af[ks] = *(bf16x8*)v;
    sf[ks] = *(const bf16x8*)&stbf[(size_t)row * DDIM + ks * 32 + cb];
  }

  for (int ct = 0; ct < 12; ct++) {
    const int c = ct * 16 + col16;
    f32x4 ir = bc4(bih[c]), iz = bc4(bih[c + DDIM]), in_ = bc4(bih[c + 2 * DDIM]);
    f32x4 hr = bc4(bhh[c]), hz = bc4(bhh[c + DDIM]), hn = bc4(bhh[c + 2 * DDIM]);
#pragma unroll
    for (int ks = 0; ks < 6; ks++) {
      const bf16x8 wr = *(const bf16x8*)&pWih[((size_t)(ks * 36 + ct) * 64 + l) * 8];
      const bf16x8 wz = *(const bf16x8*)&pWih[((size_t)(ks * 36 + ct + 12) * 64 + l) * 8];
      const bf16x8 wn = *(const bf16x8*)&pWih[((size_t)(ks * 36 + ct + 24) * 64 + l) * 8];
      ir  = __builtin_amdgcn_mfma_f32_16x16x32_bf16(af[ks], wr, ir, 0, 0, 0);
      iz  = __builtin_amdgcn_mfma_f32_16x16x32_bf16(af[ks], wz, iz, 0, 0, 0);
      in_ = __builtin_amdgcn_mfma_f32_16x16x32_bf16(af[ks], wn, in_, 0, 0, 0);
      const bf16x8 vr = *(const bf16x8*)&pWhh[((size_t)(ks * 36 + ct) * 64 + l) * 8];
      const bf16x8 vz = *(const bf16x8*)&pWhh[((size_t)(ks * 36 + ct + 12) * 64 + l) * 8];
      const bf16x8 vn = *(const bf16x8*)&pWhh[((size_t)(ks * 36 + ct + 24) * 64 + l) * 8];
      hr = __builtin_amdgcn_mfma_f32_16x16x32_bf16(sf[ks], vr, hr, 0, 0, 0);
      hz = __builtin_amdgcn_mfma_f32_16x16x32_bf16(sf[ks], vz, hz, 0, 0, 0);
      hn = __builtin_amdgcn_mfma_f32_16x16x32_bf16(sf[ks], vn, hn, 0, 0, 0);
    }
#pragma unroll
    for (int j = 0; j < 4; j++) {
      const size_t idx = (size_t)(n0 + wid * 16 + rr + j) * DDIM + c;
      const float sv = bf2f(stbf[idx]);
      const float r = sigm(ir[j] + hr[j]);
      const float z = sigm(iz[j] + hz[j]);
      const float nn = tanhf_(in_[j] + r * hn[j]);
      stbf[idx] = (unsigned short)f2bf((1.0f - z) * nn + z * sv);
    }
  }
}

// ---------------- MFMA head v4: 32 rows/block, 256 threads (4 waves), LDS 32KB
// -> 5 blocks/CU. Wave = (branch b = wid>>1, col-half cw = wid&1).
__global__ __launch_bounds__(256, 5) void k_head_mfma(
    const unsigned short* __restrict__ stbf, const int* __restrict__ nig,
    const float* __restrict__ label, const int* __restrict__ subidx,
    const short* __restrict__ pWt1, const float* __restrict__ bt1,
    const short* __restrict__ pWt2, const float* __restrict__ bt2,
    const short* __restrict__ pWt3, const float* __restrict__ bt3,
    const short* __restrict__ pWa1, const float* __restrict__ ba1,
    const short* __restrict__ pWa2, const float* __restrict__ ba2,
    const short* __restrict__ pWa3, const float* __restrict__ ba3,
    float* __restrict__ REP) {
  __shared__ short u1[8192];   // pd [rt<2][ks<6][64][8] (12KB of 16KB) / ph2 t+a (8+8KB)
  __shared__ short ph1[8192];  // ph1 t+a, each [rt<2][ks<4][64][8]; la/lse overlay after L2
  float* la  = (float*)ph1;    // [32][KMIX], valid after post-L2 barrier
  float* lse = la + 32 * KMIX;

  const int t = threadIdx.x;
  const int r0 = blockIdx.x * 32;
  float* rep = REP + (size_t)(blockIdx.x & (NREP - 1)) * REP_STRIDE;

  if (t < 32) {
    const int gr = r0 + t;
    if (gr < NEOUT) atomicAdd(&rep[CNT_OFF + subidx[gr]], 1.0f);
  }

  // stage diff A-frags into pd (u1), swizzled: 768 tasks = 32 rows x 24 groups
  for (int it = 0; it < 3; it++) {
    const int id = t + 256 * it;
    const int r = id / 24, g24 = id % 24;
    const int gr = r0 + r;
    const int ok = (gr < NEOUT);
    const int ia = ok ? nig[2 * gr] : 0;
    const int ib = ok ? nig[2 * gr + 1] : 0;   // ia==ib -> zero diff on pad rows
    const u16x8 a = *(const u16x8*)&stbf[(size_t)ia * DDIM + g24 * 8];
    const u16x8 b = *(const u16x8*)&stbf[(size_t)ib * DDIM + g24 * 8];
    short v[8];
#pragma unroll
    for (int j = 0; j < 8; j++) v[j] = f2bf(bf2f(a[j]) - bf2f(b[j]));
    const int rt = r >> 4, ks = g24 >> 2, g = g24 & 3;
    *(bf16x8*)&u1[swz((rt * 6 + ks) * 64 + g * 16 + (r & 15)) * 8] = *(bf16x8*)v;
  }
  __syncthreads();

  const int wid = t >> 6, l = t & 63;
  const int b = wid >> 1, cw = wid & 1;
  const int col16 = l & 15, rr = (l >> 4) * 4;

  const short* pW1 = b ? pWa1 : pWt1;
  const short* pW2 = b ? pWa2 : pWt2;
  const short* pW3 = b ? pWa3 : pWt3;
  const float* bv1 = b ? ba1 : bt1;
  const float* bv2 = b ? ba2 : bt2;
  const float* bv3 = b ? ba3 : bt3;
  short* ph1b = ph1 + b * 4096;
  short* ph2b = u1 + b * 4096;

  // ---- L1: K=192; this wave's 4 cts in 2 pairs; B persistent per pair ----
  for (int cp = 0; cp < 2; cp++) {
    bf16x8 B1[12];
    float bias[2];
#pragma unroll
    for (int c2 = 0; c2 < 2; c2++) {
      const int ct = cw * 4 + cp * 2 + c2;
      bias[c2] = bv1[ct * 16 + col16];
#pragma unroll
      for (int ks = 0; ks < 6; ks++)
        B1[c2 * 6 + ks] = *(const bf16x8*)&pW1[((ks * 8 + ct) * 64 + l) * 8];
    }
#pragma unroll
    for (int rt = 0; rt < 2; rt++) {
      bf16x8 a[6];
#pragma unroll
      for (int ks = 0; ks < 6; ks++)
        a[ks] = *(const bf16x8*)&u1[swz((rt * 6 + ks) * 64 + l) * 8];
      f32x4 acc0 = bc4(bias[0]), acc1 = bc4(bias[1]);
#pragma unroll
      for (int ks = 0; ks < 6; ks++) {
        acc0 = __builtin_amdgcn_mfma_f32_16x16x32_bf16(a[ks], B1[ks], acc0, 0, 0, 0);
        acc1 = __builtin_amdgcn_mfma_f32_16x16x32_bf16(a[ks], B1[6 + ks], acc1, 0, 0, 0);
      }
#pragma unroll
      for (int c2 = 0; c2 < 2; c2++) {
        const int col = (cw * 4 + cp * 2 + c2) * 16 + col16;
        const int ksp = col >> 5, gp = (col & 31) >> 3, jp = col & 7;
        const f32x4 acc = c2 ? acc1 : acc0;
#pragma unroll
        for (int j = 0; j < 4; j++)
          ph1b[swz((rt * 4 + ksp) * 64 + gp * 16 + rr + j) * 8 + jp] = f2bf(fmaxf(acc[j], 0.0f));
      }
    }
  }
  __syncthreads();   // pd dead; ph1 complete

  // ---- L2: K=128 ----
  for (int cp = 0; cp < 2; cp++) {
    bf16x8 B2[8];
    float bias[2];
#pragma unroll
    for (int c2 = 0; c2 < 2; c2++) {
      const int ct = cw * 4 + cp * 2 + c2;
      bias[c2] = bv2[ct * 16 + col16];
#pragma unroll
      for (int ks = 0; ks < 4; ks++)
        B2[c2 * 4 + ks] = *(const bf16x8*)&pW2[((ks * 8 + ct) * 64 + l) * 8];
    }
#pragma unroll
    for (int rt = 0; rt < 2; rt++) {
      bf16x8 a[4];
#pragma unroll
      for (int ks = 0; ks < 4; ks++)
        a[ks] = *(const bf16x8*)&ph1b[swz((rt * 4 + ks) * 64 + l) * 8];
      f32x4 acc0 = bc4(bias[0]), acc1 = bc4(bias[1]);
#pragma unroll
      for (int ks = 0; ks < 4; ks++) {
        acc0 = __builtin_amdgcn_mfma_f32_16x16x32_bf16(a[ks], B2[ks], acc0, 0, 0, 0);
        acc1 = __builtin_amdgcn_mfma_f32_16x16x32_bf16(a[ks], B2[4 + ks], acc1, 0, 0, 0);
      }
#pragma unroll
      for (int c2 = 0; c2 < 2; c2++) {
        const int col = (cw * 4 + cp * 2 + c2) * 16 + col16;
        const int ksp = col >> 5, gp = (col & 31) >> 3, jp = col & 7;
        const f32x4 acc = c2 ? acc1 : acc0;
#pragma unroll
        for (int j = 0; j < 4; j++)
          ph2b[swz((rt * 4 + ksp) * 64 + gp * 16 + rr + j) * 8 + jp] = f2bf(fmaxf(acc[j], 0.0f));
      }
    }
  }
  __syncthreads();   // ph1 dead (la/lse may now use it); ph2 complete

  // ---- L3: K=128, N=32 (cols>=20 zero-padded); ct3 = cw ----
  {
    const int col = cw * 16 + col16;
    bf16x8 B3[4];
#pragma unroll
    for (int ks = 0; ks < 4; ks++)
      B3[ks] = *(const bf16x8*)&pW3[((ks * 2 + cw) * 64 + l) * 8];
    const float bias = (col < KMIX) ? bv3[col] : 0.0f;
#pragma unroll
    for (int rt = 0; rt < 2; rt++) {
      bf16x8 a[4];
#pragma unroll
      for (int ks = 0; ks < 4; ks++)
        a[ks] = *(const bf16x8*)&ph2b[swz((rt * 4 + ks) * 64 + l) * 8];
      f32x4 acc = bc4(bias);
#pragma unroll
      for (int ks = 0; ks < 4; ks++)
        acc = __builtin_amdgcn_mfma_f32_16x16x32_bf16(a[ks], B3[ks], acc, 0, 0, 0);
      if (col < KMIX) {
        if (b == 0) {
#pragma unroll
          for (int j = 0; j < 4; j++) {
            const int r = rt * 16 + rr + j;
            const int gr = r0 + r;
            if (gr < NEOUT) {
              const float lt = acc[j];
              const float adj = fmaxf(lt, 0.0f) + logf(1.0f + __expf(-fabsf(lt)))
                                - lt * label[gr];
              atomicAdd(&rep[LOSS_OFF + subidx[gr] * KMIX + col], adj);
            }
          }
        } else {
#pragma unroll
          for (int j = 0; j < 4; j++)
            la[(rt * 16 + rr + j) * KMIX + col] = acc[j];
        }
      }
    }
  }
  __syncthreads();
  if (t < 32) {
    float m = -1e30f;
    for (int k = 0; k < KMIX; k++) m = fmaxf(m, la[t * KMIX + k]);
    float s = 0.0f;
    for (int k = 0; k < KMIX; k++) s += __expf(la[t * KMIX + k] - m);
    lse[t] = m + logf(s);
  }
  __syncthreads();
  {
    const int r = t >> 3;
    const int gr = r0 + r;
    if (gr < NEOUT) {
      const int sb = subidx[gr];
#pragma unroll
      for (int i = 0; i < 3; i++) {
        const int c = (t & 7) + 8 * i;
        if (c < KMIX)
          atomicAdd(&rep[ALPHA_OFF + sb * KMIX + c], la[r * KMIX + c] - lse[r]);
      }
    }
  }
}

// ---------------- fold 64 replicas into final arrays (coalesced)
__global__ __launch_bounds__(256) void k_red(const float* __restrict__ REP,
                                             float* __restrict__ fin) {
  const int i = blockIdx.x * 256 + threadIdx.x;
  if (i < REP_STRIDE) {
    float s = 0.0f;
    for (int r = 0; r < NREP; r++) s += REP[(size_t)r * REP_STRIDE + i];
    fin[i] = s;
  }
}

// ---------------- final: per-subgraph logsumexp, reduce to scalar
__global__ __launch_bounds__(1024) void k_final(
    const float* __restrict__ fin, float* __restrict__ out) {
  __shared__ float part[1024];
  const int s = threadIdx.x;
  const float* red_loss  = fin + LOSS_OFF;
  const float* red_alpha = fin + ALPHA_OFF;
  const float c = fmaxf(fin[CNT_OFF + s], 1.0f);
  float v[KMIX];
  float m = -1e30f;
  for (int k = 0; k < KMIX; k++) {
    v[k] = -red_loss[s * KMIX + k] + red_alpha[s * KMIX + k] / c;
    m = fmaxf(m, v[k]);
  }
  float sum = 0.0f;
  for (int k = 0; k < KMIX; k++) sum += __expf(v[k] - m);
  part[s] = m + logf(sum);
  __syncthreads();
  for (int st = 512; st > 0; st >>= 1) {
    if (s < st) part[s] += part[s + st];
    __syncthreads();
  }
  if (s == 0) out[0] = -part[0] / (float)NEOUT;
}

extern "C" void kernel_launch(void* const* d_in, const int* in_sizes, int n_in,
                              void* d_out, int out_size, void* d_ws, size_t ws_size,
                              hipStream_t stream) {
  const float* A      = (const float*)d_in[0];
  const int*   edges  = (const int*)d_in[1];
  const int*   attidx = (const int*)d_in[2];
  const int*   nif    = (const int*)d_in[3];
  const int*   cl     = (const int*)d_in[4];
  const int*   nig    = (const int*)d_in[5];
  const float* label  = (const float*)d_in[6];
  const int*   subidx = (const int*)d_in[7];
  const float* Wdec   = (const float*)d_in[8];
  const float* bdec   = (const float*)d_in[9];
  const float* cemb   = (const float*)d_in[10];
  const float* Wm1    = (const float*)d_in[11];
  const float* bm1    = (const float*)d_in[12];
  const float* Wm2    = (const float*)d_in[13];
  const float* bm2    = (const float*)d_in[14];
  const float* Wa1    = (const float*)d_in[15];
  const float* ba1    = (const float*)d_in[16];
  const float* Wa2    = (const float*)d_in[17];
  const float* ba2    = (const float*)d_in[18];
  const float* Wih    = (const float*)d_in[19];
  const float* bih    = (const float*)d_in[20];
  const float* Whh    = (const float*)d_in[21];
  const float* bhh    = (const float*)d_in[22];
  const float* Wt1    = (const float*)d_in[23];
  const float* bt1    = (const float*)d_in[24];
  const float* Wt2    = (const float*)d_in[25];
  const float* bt2    = (const float*)d_in[26];
  const float* Wt3    = (const float*)d_in[27];
  const float* bt3    = (const float*)d_in[28];
  const float* Wha1   = (const float*)d_in[29];
  const float* hba1   = (const float*)d_in[30];
  const float* Wha2   = (const float*)d_in[31];
  const float* hba2   = (const float*)d_in[32];
  const float* Wha3   = (const float*)d_in[33];
  const float* hba3   = (const float*)d_in[34];

  char* ws = (char*)d_ws;
  const size_t SZ_STBF = (size_t)NGNN * DDIM * sizeof(short);     // 12,582,912
  const size_t SZ_MSG  = (size_t)NEDGE * DDIM * sizeof(short);    // 76,800,000
  const size_t SZ_REP  = (size_t)NREP * REP_STRIDE * sizeof(float); // 10.75 MB

  unsigned short* stbf   = (unsigned short*)ws;
  unsigned short* msgbuf = (unsigned short*)(ws + SZ_STBF);
  // overlays inside the msgbuf region (disjoint lifetimes, stream-ordered):
  float* nf  = (float*)(ws + SZ_STBF);            // dec output, dead before edge
  float* REP = (float*)(ws + SZ_STBF);            // used only after last gru
  float* fin = (float*)(ws + SZ_STBF + SZ_REP);

  char* tail = ws + SZ_STBF + SZ_MSG;
  int* rowptr = (int*)tail;                       // (NGNN+1) ints, pad to 131,328
  int* degcur = (int*)(tail + 131328);            // NGNN ints (deg, then cursor)
  int* eidx   = (int*)(tail + 131328 + 131072);   // NEDGE ints = 800,000 B
  short* pk   = (short*)(tail + 131328 + 131072 + 800000);
  short* pWm1  = pk;             // K=320: 10*12*512
  short* pWa1e = pWm1  + 61440;  // K=320: 10*8*512
  short* pWm2  = pWa1e + 40960;  // 6*12*512
  short* pWa2e = pWm2  + 36864;  // 4*12*512
  short* pWt1  = pWa2e + 24576;  // 6*8*512
  short* pWt2  = pWt1  + 24576;  // 4*8*512
  short* pWt3  = pWt2  + 16384;  // 4*2*512
  short* pWh1  = pWt3  + 4096;   // 6*8*512
  short* pWh2  = pWh1  + 24576;  // 4*8*512
  short* pWh3  = pWh2  + 16384;  // 4*2*512
  short* pWih  = pWh3  + 4096;   // 6*36*512
  short* pWhh  = pWih  + 110592; // 6*36*512

  // CSR build by dst (once; edges are constant across props)
  hipMemsetAsync(degcur, 0, (size_t)NGNN * sizeof(int), stream);
  k_hist<<<(NEDGE + 255) / 256, 256, 0, stream>>>(edges, degcur);
  k_scan<<<1, 1024, 0, stream>>>(degcur, rowptr, degcur);
  k_scatter<<<(NEDGE + 255) / 256, 256, 0, stream>>>(edges, degcur, eidx);

  // pack weights to bf16 B-fragment layout (grid = (K/32)*CT)
  k_pack<<<120, 64, 0, stream>>>(Wm1,  pWm1,  192, 12);   // K=320
  k_pack<<< 80, 64, 0, stream>>>(Wa1,  pWa1e, 128, 8);    // K=320
  k_pack<<< 72, 64, 0, stream>>>(Wm2,  pWm2,  192, 12);
  k_pack<<< 48, 64, 0, stream>>>(Wa2,  pWa2e, 192, 12);
  k_pack<<< 48, 64, 0, stream>>>(Wt1,  pWt1,  128, 8);
  k_pack<<< 32, 64, 0, stream>>>(Wt2,  pWt2,  128, 8);
  k_pack<<<  8, 64, 0, stream>>>(Wt3,  pWt3,   20, 2);
  k_pack<<< 48, 64, 0, stream>>>(Wha1, pWh1,  128, 8);
  k_pack<<< 32, 64, 0, stream>>>(Wha2, pWh2,  128, 8);
  k_pack<<<  8, 64, 0, stream>>>(Wha3, pWh3,   20, 2);
  k_pack<<<216, 64, 0, stream>>>(Wih,  pWih,  576, 36);
  k_pack<<<216, 64, 0, stream>>>(Whh,  pWhh,  576, 36);

  k_dec<<<NGNN, 128, 0, stream>>>(A, Wdec, bdec, nf);
  k_state<<<NGNN, 192, 0, stream>>>(nf, cemb, nif, cl, stbf);
  for (int p = 0; p < 2; p++) {
    k_edge_mfma<<<NEDGE / 32, 256, 0, stream>>>(stbf, edges, attidx,
        bm1, pWm1, pWm2, bm2, ba1, pWa1e, pWa2e, ba2, msgbuf);
    k_gru_mfma<<<NGNN / 64, 256, 0, stream>>>(stbf, msgbuf, rowptr, eidx,
        pWih, bih, pWhh, bhh);
  }
  hipMemsetAsync(REP, 0, SZ_REP, stream);
  k_head_mfma<<<(NEOUT + 31) / 32, 256, 0, stream>>>(stbf, nig, label, subidx,
      pWt1, bt1, pWt2, bt2, pWt3, bt3, pWh1, hba1, pWh2, hba2, pWh3, hba3, REP);
  k_red<<<(REP_STRIDE + 255) / 256, 256, 0, stream>>>(REP, fin);
  k_final<<<1, 1024, 0, stream>>>(fin, (float*)d_out);
}

// Round 14
// 859.904 us; speedup vs baseline: 1.4086x; 1.4086x over previous
//
#include <hip/hip_runtime.h>
#include <math.h>

#define NGNN   32768
#define NMAXD  1024
#define HIDD   128
#define CLSD   64
#define DDIM   192
#define ATTH   128
#define NEDGE  200000
#define NEOUT  500000
#define NSUB   1024
#define KMIX   20

#define NREP      64
#define LOSS_OFF  0
#define ALPHA_OFF 20480
#define CNT_OFF   40960
#define REP_STRIDE 41984

typedef __attribute__((ext_vector_type(8))) short bf16x8;
typedef __attribute__((ext_vector_type(8))) unsigned short u16x8;
typedef __attribute__((ext_vector_type(4))) float f32x4;

__device__ __forceinline__ float sigm(float x) { return 1.0f / (1.0f + __expf(-x)); }
__device__ __forceinline__ float tanhf_(float x) { return 2.0f / (1.0f + __expf(-2.0f * x)) - 1.0f; }

__device__ __forceinline__ short f2bf(float f) {
  union { float f; unsigned u; } v; v.f = f;
  unsigned r = v.u + 0x7FFFu + ((v.u >> 16) & 1u);
  return (short)(r >> 16);
}
__device__ __forceinline__ float bf2f(unsigned short u) {
  union { unsigned u; float f; } v; v.u = ((unsigned)u) << 16;
  return v.f;
}
__device__ __forceinline__ f32x4 bc4(float b) {
  f32x4 v; v[0] = b; v[1] = b; v[2] = b; v[3] = b; return v;
}
// bank swizzle on 16B-unit index (bijective involution) — used in HEAD only
__device__ __forceinline__ int swz(int u) { return u ^ ((u >> 4) & 7); }

// ---------------- CSR build (once): histogram by dst, scan, scatter
__global__ __launch_bounds__(256) void k_hist(const int* __restrict__ edges,
                                              int* __restrict__ deg) {
  const int e = blockIdx.x * 256 + threadIdx.x;
  if (e < NEDGE) atomicAdd(&deg[edges[2 * e + 1]], 1);
}

__global__ __launch_bounds__(1024) void k_scan(const int* deg_in,
                                               int* rowptr, int* cursor) {
  __shared__ int part[1024];
  const int t = threadIdx.x;
  const int base = t * 32;
  int loc[32];
  int s = 0;
#pragma unroll
  for (int i = 0; i < 32; i++) { loc[i] = deg_in[base + i]; s += loc[i]; }
  part[t] = s;
  __syncthreads();
  for (int off = 1; off < 1024; off <<= 1) {
    int v = 0;
    if (t >= off) v = part[t - off];
    __syncthreads();
    part[t] += v;
    __syncthreads();
  }
  int pre = (t == 0) ? 0 : part[t - 1];
#pragma unroll
  for (int i = 0; i < 32; i++) {
    rowptr[base + i] = pre;
    cursor[base + i] = pre;
    pre += loc[i];
  }
  if (t == 1023) rowptr[NGNN] = pre;
}

__global__ __launch_bounds__(256) void k_scatter(const int* __restrict__ edges,
                                                 int* __restrict__ cursor,
                                                 int* __restrict__ eidx) {
  const int e = blockIdx.x * 256 + threadIdx.x;
  if (e < NEDGE) {
    const int p = atomicAdd(&cursor[edges[2 * e + 1]], 1);
    eidx[p] = e;
  }
}

// ---------------- pack fp32 [K][N] weight into bf16 MFMA B-fragment order
__global__ __launch_bounds__(64) void k_pack(const float* __restrict__ W,
                                             short* __restrict__ out, int N, int CT) {
  const int l = threadIdx.x;
  const int ks = blockIdx.x / CT;
  const int ct = blockIdx.x % CT;
  const int row0 = ks * 32 + (l >> 4) * 8;
  const int col = ct * 16 + (l & 15);
  short v[8];
#pragma unroll
  for (int j = 0; j < 8; j++) {
    const float f = (col < N) ? W[(size_t)(row0 + j) * N + col] : 0.0f;
    v[j] = f2bf(f);
  }
  *(bf16x8*)(out + ((size_t)blockIdx.x * 64 + l) * 8) = *(bf16x8*)v;
}

// ---------------- nf = A @ W_dec + b_dec, exploiting A in {0,1} with ~5% density
__global__ __launch_bounds__(128) void k_dec(
    const float* __restrict__ A, const float* __restrict__ Wd,
    const float* __restrict__ bd, float* __restrict__ nf) {
  __shared__ float arow[NMAXD];
  __shared__ int   nz[NMAXD];
  __shared__ int   cnt;
  const int row = blockIdx.x;
  const int t = threadIdx.x;
  if (t == 0) cnt = 0;
  const float4* A4 = (const float4*)(A + (size_t)row * NMAXD);
  float4* a4 = (float4*)arow;
  a4[t] = A4[t];
  a4[t + 128] = A4[t + 128];
  __syncthreads();
  for (int i = t; i < NMAXD; i += 128) {
    if (arow[i] != 0.0f) {
      int p = atomicAdd(&cnt, 1);
      nz[p] = i;
    }
  }
  __syncthreads();
  float acc = bd[t];
  const int n = cnt;
  for (int i = 0; i < n; i++) acc += Wd[(size_t)nz[i] * HIDD + t];
  nf[(size_t)row * HIDD + t] = acc;
}

// ---------------- stbf[i] = bf16(concat(nf[nif[i]] (0-row aware), class_emb[cl[i]]))
__global__ __launch_bounds__(192) void k_state(
    const float* __restrict__ nf, const float* __restrict__ cemb,
    const int* __restrict__ nif, const int* __restrict__ cl,
    unsigned short* __restrict__ stbf) {
  const int i = blockIdx.x;
  const int t = threadIdx.x;
  float v;
  if (t < HIDD) {
    const int idx = nif[i];
    v = (idx == 0) ? 0.0f : nf[(size_t)(idx - 1) * HIDD + t];
  } else {
    v = cemb[cl[i] * CLSD + (t - HIDD)];
  }
  stbf[(size_t)i * DDIM + t] = (unsigned short)f2bf(v);
}

// ---------------- MFMA edge kernel v5 (round-10 config, NO swizzle):
// 64 edges/block, 256 threads (4 waves). Outer-product column-split,
// K=320 in-register one-hot, no atomics (msgbuf).
__global__ __launch_bounds__(256, 2) void k_edge_mfma(
    const unsigned short* __restrict__ stbf, const int* __restrict__ edges,
    const int* __restrict__ attidx,
    const float* __restrict__ bm1,
    const short* __restrict__ pWm1, const short* __restrict__ pWm2,
    const float* __restrict__ bm2,
    const float* __restrict__ ba1,
    const short* __restrict__ pWa1, const short* __restrict__ pWa2,
    const float* __restrict__ ba2,
    unsigned short* __restrict__ msgbuf) {
  __shared__ short pdiff[12288];  // [rt<4][ks<6][64][8] 24KB; later msgrow[64][192]
  __shared__ short phm[12288];    // hm A-frags (K=192)  24KB
  __shared__ short pha[8192];     // ha A-frags (K=128)  16KB
  __shared__ int   sa0[64], sa1[64];

  const int t = threadIdx.x;
  const int e0 = blockIdx.x * 64;
  const int wid = t >> 6, l = t & 63;
  const int col16 = l & 15, rr = (l >> 4) * 4;
  const int cb = (l >> 4) * 8;

  if (t < 64) {
    const int s = edges[2 * (e0 + t)];
    const int d = edges[2 * (e0 + t) + 1];
    sa0[t] = attidx[s] + 192;
    sa1[t] = attidx[d] + 256;
  }
  // stage diff A-frags
  for (int it = 0; it < 6; it++) {
    const int id = t + 256 * it;      // 1536 tasks: 64 rows x 24 col-groups
    const int r = id / 24, g24 = id % 24;
    const int e = e0 + r;
    const int s = edges[2 * e], d = edges[2 * e + 1];
    const u16x8 a = *(const u16x8*)&stbf[(size_t)s * DDIM + g24 * 8];
    const u16x8 b = *(const u16x8*)&stbf[(size_t)d * DDIM + g24 * 8];
    short v[8];
#pragma unroll
    for (int j = 0; j < 8; j++) v[j] = f2bf(bf2f(a[j]) - bf2f(b[j]));
    const int rt = r >> 4, ks = g24 >> 2, g = g24 & 3;
    *(bf16x8*)&pdiff[((rt * 6 + ks) * 64 + g * 16 + (r & 15)) * 8] = *(bf16x8*)v;
  }
  __syncthreads();

  // per-lane one-hot targets for row (l&15) of each row-tile
  int a0v[4], a1v[4];
#pragma unroll
  for (int rt = 0; rt < 4; rt++) {
    a0v[rt] = sa0[rt * 16 + (l & 15)];
    a1v[rt] = sa1[rt * 16 + (l & 15)];
  }

  const int w5 = wid * 5;

  // ---- L1: [64x320] @ [320x(192|128)] fused, ks-outer outer-product ----
  {
    f32x4 acc[5][4];
#pragma unroll
    for (int u = 0; u < 5; u++)
#pragma unroll
      for (int rt = 0; rt < 4; rt++) acc[u][rt] = bc4(0.0f);

    for (int ks = 0; ks < 10; ks++) {
      bf16x8 A[4];
      if (ks < 6) {
#pragma unroll
        for (int rt = 0; rt < 4; rt++)
          A[rt] = *(const bf16x8*)&pdiff[((rt * 6 + ks) * 64 + l) * 8];
      } else {
        const int kb = ks * 32 + cb;
#pragma unroll
        for (int rt = 0; rt < 4; rt++) {
          short v[8];
#pragma unroll
          for (int j = 0; j < 8; j++) {
            const int kg = kb + j;
            v[j] = (kg == a0v[rt] || kg == a1v[rt]) ? (short)0x3F80 : (short)0;
          }
          A[rt] = *(bf16x8*)v;
        }
      }
      bf16x8 B[5];
#pragma unroll
      for (int u = 0; u < 5; u++) {
        const int unit = w5 + u;
        const short* bp = (unit < 12)
            ? &pWm1[((ks * 12 + unit) * 64 + l) * 8]
            : &pWa1[((ks * 8 + (unit - 12)) * 64 + l) * 8];
        B[u] = *(const bf16x8*)bp;
      }
#pragma unroll
      for (int u = 0; u < 5; u++)
#pragma unroll
        for (int rt = 0; rt < 4; rt++)
          acc[u][rt] = __builtin_amdgcn_mfma_f32_16x16x32_bf16(A[rt], B[u], acc[u][rt], 0, 0, 0);
    }

    // bias + relu + relayout to phm/pha
#pragma unroll
    for (int u = 0; u < 5; u++) {
      const int unit = w5 + u;
      const int isMsg = (unit < 12);
      const int ct = isMsg ? unit : unit - 12;
      const int col = ct * 16 + col16;
      const float bb = isMsg ? bm1[col] : ba1[col];
      const int ksp = col >> 5, gp = (col & 31) >> 3, jp = col & 7;
#pragma unroll
      for (int rt = 0; rt < 4; rt++)
#pragma unroll
        for (int j = 0; j < 4; j++) {
          const short hv = f2bf(fmaxf(acc[u][rt][j] + bb, 0.0f));
          if (isMsg) phm[((rt * 6 + ksp) * 64 + gp * 16 + rr + j) * 8 + jp] = hv;
          else       pha[((rt * 4 + ksp) * 64 + gp * 16 + rr + j) * 8 + jp] = hv;
        }
    }
  }
  __syncthreads();

  // ---- L2: wave owns 3 of 12 output cts x 4 rts ----
  {
    const int w3 = wid * 3;
    f32x4 m[3][4], av[3][4];
#pragma unroll
    for (int c = 0; c < 3; c++) {
      const int col = (w3 + c) * 16 + col16;
      const f32x4 bm = bc4(bm2[col]), ba = bc4(ba2[col]);
#pragma unroll
      for (int rt = 0; rt < 4; rt++) { m[c][rt] = bm; av[c][rt] = ba; }
    }
    for (int ks = 0; ks < 6; ks++) {
      bf16x8 A[4];
#pragma unroll
      for (int rt = 0; rt < 4; rt++)
        A[rt] = *(const bf16x8*)&phm[((rt * 6 + ks) * 64 + l) * 8];
      bf16x8 B[3];
#pragma unroll
      for (int c = 0; c < 3; c++)
        B[c] = *(const bf16x8*)&pWm2[((ks * 12 + w3 + c) * 64 + l) * 8];
#pragma unroll
      for (int c = 0; c < 3; c++)
#pragma unroll
        for (int rt = 0; rt < 4; rt++)
          m[c][rt] = __builtin_amdgcn_mfma_f32_16x16x32_bf16(A[rt], B[c], m[c][rt], 0, 0, 0);
    }
    for (int ks = 0; ks < 4; ks++) {
      bf16x8 A[4];
#pragma unroll
      for (int rt = 0; rt < 4; rt++)
        A[rt] = *(const bf16x8*)&pha[((rt * 4 + ks) * 64 + l) * 8];
      bf16x8 B[3];
#pragma unroll
      for (int c = 0; c < 3; c++)
        B[c] = *(const bf16x8*)&pWa2[((ks * 12 + w3 + c) * 64 + l) * 8];
#pragma unroll
      for (int c = 0; c < 3; c++)
#pragma unroll
        for (int rt = 0; rt < 4; rt++)
          av[c][rt] = __builtin_amdgcn_mfma_f32_16x16x32_bf16(A[rt], B[c], av[c][rt], 0, 0, 0);
    }

    // write combined values to LDS msgrow (overlays pdiff; dead since L1 + barrier)
    short* msgrow = pdiff;
#pragma unroll
    for (int c = 0; c < 3; c++) {
      const int col = (w3 + c) * 16 + col16;
#pragma unroll
      for (int rt = 0; rt < 4; rt++)
#pragma unroll
        for (int j = 0; j < 4; j++)
          msgrow[(rt * 16 + rr + j) * DDIM + col] = f2bf(m[c][rt][j] * sigm(av[c][rt][j]));
    }
  }
  __syncthreads();

  // coalesced copy msgrow -> msgbuf (64 rows x 384B)
  {
    const short* msgrow = pdiff;
    for (int it = 0; it < 6; it++) {
      const int id = t + 256 * it;      // 1536 tasks
      const int r = id / 24, g = id % 24;
      *(float4*)&msgbuf[(size_t)(e0 + r) * DDIM + g * 8] =
          *(const float4*)&msgrow[r * DDIM + g * 8];
    }
  }
}

// ---------------- MFMA GRU: 64 nodes/block, 256 threads (4 waves), zero LDS.
__global__ __launch_bounds__(256, 2) void k_gru_mfma(
    unsigned short* __restrict__ stbf,
    const unsigned short* __restrict__ msgbuf,
    const int* __restrict__ rowptr, const int* __restrict__ eidx,
    const short* __restrict__ pWih, const float* __restrict__ bih,
    const short* __restrict__ pWhh, const float* __restrict__ bhh) {
  const int t = threadIdx.x;
  const int n0 = blockIdx.x * 64;
  const int wid = t >> 6, l = t & 63;
  const int col16 = l & 15, rr = (l >> 4) * 4;
  const int cb = (l >> 4) * 8;
  const int row = n0 + wid * 16 + (l & 15);

  float afacc[6][8];
#pragma unroll
  for (int ks = 0; ks < 6; ks++)
#pragma unroll
    for (int j = 0; j < 8; j++) afacc[ks][j] = 0.0f;

  const int rbeg = rowptr[row], rend = rowptr[row + 1];
  for (int p = rbeg; p < rend; p++) {
    const int e = eidx[p];
    const unsigned short* mr = &msgbuf[(size_t)e * DDIM + cb];
#pragma unroll
    for (int ks = 0; ks < 6; ks++) {
      const u16x8 cc = *(const u16x8*)(mr + ks * 32);
#pragma unroll
      for (int j = 0; j < 8; j++) afacc[ks][j] += bf2f(cc[j]);
    }
  }

  bf16x8 af[6], sf[6];
#pragma unroll
  for (int ks = 0; ks < 6; ks++) {
    short v[8];
#pragma unroll
    for (int j = 0; j < 8; j++) v[j] = f2bf(afacc[ks][j]);
    af[ks] = *(bf16x8*)v;
    sf[ks] = *(const bf16x8*)&stbf[(size_t)row * DDIM + ks * 32 + cb];
  }

  for (int ct = 0; ct < 12; ct++) {
    const int c = ct * 16 + col16;
    f32x4 ir = bc4(bih[c]), iz = bc4(bih[c + DDIM]), in_ = bc4(bih[c + 2 * DDIM]);
    f32x4 hr = bc4(bhh[c]), hz = bc4(bhh[c + DDIM]), hn = bc4(bhh[c + 2 * DDIM]);
#pragma unroll
    for (int ks = 0; ks < 6; ks++) {
      const bf16x8 wr = *(const bf16x8*)&pWih[((size_t)(ks * 36 + ct) * 64 + l) * 8];
      const bf16x8 wz = *(const bf16x8*)&pWih[((size_t)(ks * 36 + ct + 12) * 64 + l) * 8];
      const bf16x8 wn = *(const bf16x8*)&pWih[((size_t)(ks * 36 + ct + 24) * 64 + l) * 8];
      ir  = __builtin_amdgcn_mfma_f32_16x16x32_bf16(af[ks], wr, ir, 0, 0, 0);
      iz  = __builtin_amdgcn_mfma_f32_16x16x32_bf16(af[ks], wz, iz, 0, 0, 0);
      in_ = __builtin_amdgcn_mfma_f32_16x16x32_bf16(af[ks], wn, in_, 0, 0, 0);
      const bf16x8 vr = *(const bf16x8*)&pWhh[((size_t)(ks * 36 + ct) * 64 + l) * 8];
      const bf16x8 vz = *(const bf16x8*)&pWhh[((size_t)(ks * 36 + ct + 12) * 64 + l) * 8];
      const bf16x8 vn = *(const bf16x8*)&pWhh[((size_t)(ks * 36 + ct + 24) * 64 + l) * 8];
      hr = __builtin_amdgcn_mfma_f32_16x16x32_bf16(sf[ks], vr, hr, 0, 0, 0);
      hz = __builtin_amdgcn_mfma_f32_16x16x32_bf16(sf[ks], vz, hz, 0, 0, 0);
      hn = __builtin_amdgcn_mfma_f32_16x16x32_bf16(sf[ks], vn, hn, 0, 0, 0);
    }
#pragma unroll
    for (int j = 0; j < 4; j++) {
      const size_t idx = (size_t)(n0 + wid * 16 + rr + j) * DDIM + c;
      const float sv = bf2f(stbf[idx]);
      const float r = sigm(ir[j] + hr[j]);
      const float z = sigm(iz[j] + hz[j]);
      const float nn = tanhf_(in_[j] + r * hn[j]);
      stbf[idx] = (unsigned short)f2bf((1.0f - z) * nn + z * sv);
    }
  }
}

// ---------------- MFMA head v3 + swizzle (round-11 config): 64 rows/block,
// 512 threads (8 waves). Wave = (branch b, col-pair cw).
__global__ __launch_bounds__(512, 4) void k_head_mfma(
    const unsigned short* __restrict__ stbf, const int* __restrict__ nig,
    const float* __restrict__ label, const int* __restrict__ subidx,
    const short* __restrict__ pWt1, const float* __restrict__ bt1,
    const short* __restrict__ pWt2, const float* __restrict__ bt2,
    const short* __restrict__ pWt3, const float* __restrict__ bt3,
    const short* __restrict__ pWa1, const float* __restrict__ ba1,
    const short* __restrict__ pWa2, const float* __restrict__ ba2,
    const short* __restrict__ pWa3, const float* __restrict__ ba3,
    float* __restrict__ REP) {
  __shared__ short u1[16384];    // pd [rt<4][ks<6][64][8] (24KB) / ph2 t+a (16+16KB)
  __shared__ short ph1[16384];   // ph1t + ph1a, each [rt<4][ks<4][64][8]
  __shared__ float la[64 * KMIX];
  __shared__ int   ssub[64];
  __shared__ float slab[64];
  __shared__ float lse[64];

  const int t = threadIdx.x;
  const int r0 = blockIdx.x * 64;
  float* rep = REP + (size_t)(blockIdx.x & (NREP - 1)) * REP_STRIDE;

  if (t < 64) {
    const int gr = r0 + t;
    const int sb = (gr < NEOUT) ? subidx[gr] : 0;
    ssub[t] = sb;
    slab[t] = (gr < NEOUT) ? label[gr] : 0.0f;
    if (gr < NEOUT) atomicAdd(&rep[CNT_OFF + sb], 1.0f);
  }

  // stage diff A-frags into pd (u1), swizzled
  for (int it = 0; it < 3; it++) {
    const int id = t + 512 * it;      // 1536 tasks: 64 rows x 24 col-groups
    const int r = id / 24, g24 = id % 24;
    const int gr = r0 + r;
    const int ok = (gr < NEOUT);
    const int ia = ok ? nig[2 * gr] : 0;
    const int ib = ok ? nig[2 * gr + 1] : 0;   // ia==ib -> zero diff on pad rows
    const u16x8 a = *(const u16x8*)&stbf[(size_t)ia * DDIM + g24 * 8];
    const u16x8 b = *(const u16x8*)&stbf[(size_t)ib * DDIM + g24 * 8];
    short v[8];
#pragma unroll
    for (int j = 0; j < 8; j++) v[j] = f2bf(bf2f(a[j]) - bf2f(b[j]));
    const int rt = r >> 4, ks = g24 >> 2, g = g24 & 3;
    *(bf16x8*)&u1[swz((rt * 6 + ks) * 64 + g * 16 + (r & 15)) * 8] = *(bf16x8*)v;
  }
  __syncthreads();

  const int wid = t >> 6, l = t & 63;
  const int b = wid >> 2, cw = wid & 3;
  const int col16 = l & 15, rr = (l >> 4) * 4;

  const short* pW1 = b ? pWa1 : pWt1;
  const short* pW2 = b ? pWa2 : pWt2;
  const short* pW3 = b ? pWa3 : pWt3;
  const float* bv1 = b ? ba1 : bt1;
  const float* bv2 = b ? ba2 : bt2;
  const float* bv3 = b ? ba3 : bt3;
  short* ph1b = ph1 + b * 8192;
  short* ph2b = u1 + b * 8192;

  // ---- L1: K=192, this wave's 2 cts; B persistent in regs ----
  {
    bf16x8 B1[12];
    float bias[2];
#pragma unroll
    for (int c2 = 0; c2 < 2; c2++) {
      const int ct = cw * 2 + c2;
      bias[c2] = bv1[ct * 16 + col16];
#pragma unroll
      for (int ks = 0; ks < 6; ks++)
        B1[c2 * 6 + ks] = *(const bf16x8*)&pW1[((ks * 8 + ct) * 64 + l) * 8];
    }
    for (int rt = 0; rt < 4; rt++) {
      bf16x8 a[6];
#pragma unroll
      for (int ks = 0; ks < 6; ks++)
        a[ks] = *(const bf16x8*)&u1[swz((rt * 6 + ks) * 64 + l) * 8];
      f32x4 acc0 = bc4(bias[0]), acc1 = bc4(bias[1]);
#pragma unroll
      for (int ks = 0; ks < 6; ks++) {
        acc0 = __builtin_amdgcn_mfma_f32_16x16x32_bf16(a[ks], B1[ks], acc0, 0, 0, 0);
        acc1 = __builtin_amdgcn_mfma_f32_16x16x32_bf16(a[ks], B1[6 + ks], acc1, 0, 0, 0);
      }
#pragma unroll
      for (int c2 = 0; c2 < 2; c2++) {
        const int col = (cw * 2 + c2) * 16 + col16;
        const int ksp = col >> 5, gp = (col & 31) >> 3, jp = col & 7;
        const f32x4 acc = c2 ? acc1 : acc0;
#pragma unroll
        for (int j = 0; j < 4; j++)
          ph1b[swz((rt * 4 + ksp) * 64 + gp * 16 + rr + j) * 8 + jp] = f2bf(fmaxf(acc[j], 0.0f));
      }
    }
  }
  __syncthreads();   // pd dead; ph1 complete

  // ---- L2: K=128 ----
  {
    bf16x8 B2[8];
    float bias[2];
#pragma unroll
    for (int c2 = 0; c2 < 2; c2++) {
      const int ct = cw * 2 + c2;
      bias[c2] = bv2[ct * 16 + col16];
#pragma unroll
      for (int ks = 0; ks < 4; ks++)
        B2[c2 * 4 + ks] = *(const bf16x8*)&pW2[((ks * 8 + ct) * 64 + l) * 8];
    }
    for (int rt = 0; rt < 4; rt++) {
      bf16x8 a[4];
#pragma unroll
      for (int ks = 0; ks < 4; ks++)
        a[ks] = *(const bf16x8*)&ph1b[swz((rt * 4 + ks) * 64 + l) * 8];
      f32x4 acc0 = bc4(bias[0]), acc1 = bc4(bias[1]);
#pragma unroll
      for (int ks = 0; ks < 4; ks++) {
        acc0 = __builtin_amdgcn_mfma_f32_16x16x32_bf16(a[ks], B2[ks], acc0, 0, 0, 0);
        acc1 = __builtin_amdgcn_mfma_f32_16x16x32_bf16(a[ks], B2[4 + ks], acc1, 0, 0, 0);
      }
#pragma unroll
      for (int c2 = 0; c2 < 2; c2++) {
        const int col = (cw * 2 + c2) * 16 + col16;
        const int ksp = col >> 5, gp = (col & 31) >> 3, jp = col & 7;
        const f32x4 acc = c2 ? acc1 : acc0;
#pragma unroll
        for (int j = 0; j < 4; j++)
          ph2b[swz((rt * 4 + ksp) * 64 + gp * 16 + rr + j) * 8 + jp] = f2bf(fmaxf(acc[j], 0.0f));
      }
    }
  }
  __syncthreads();

  // ---- L3: K=128, N=32 (cols>=20 zero-padded) ----
  {
    const int ct3 = cw & 1, rth = cw >> 1;
    const int col = ct3 * 16 + col16;
    bf16x8 B3[4];
#pragma unroll
    for (int ks = 0; ks < 4; ks++)
      B3[ks] = *(const bf16x8*)&pW3[((ks * 2 + ct3) * 64 + l) * 8];
    const float bias = (col < KMIX) ? bv3[col] : 0.0f;
#pragma unroll
    for (int i = 0; i < 2; i++) {
      const int rt = rth * 2 + i;
      bf16x8 a[4];
#pragma unroll
      for (int ks = 0; ks < 4; ks++)
        a[ks] = *(const bf16x8*)&ph2b[swz((rt * 4 + ks) * 64 + l) * 8];
      f32x4 acc = bc4(bias);
#pragma unroll
      for (int ks = 0; ks < 4; ks++)
        acc = __builtin_amdgcn_mfma_f32_16x16x32_bf16(a[ks], B3[ks], acc, 0, 0, 0);
      if (col < KMIX) {
        if (b == 0) {
#pragma unroll
          for (int j = 0; j < 4; j++) {
            const int r = rt * 16 + rr + j;
            if (r0 + r < NEOUT) {
              const float lt = acc[j];
              const float adj = fmaxf(lt, 0.0f) + logf(1.0f + __expf(-fabsf(lt))) - lt * slab[r];
              atomicAdd(&rep[LOSS_OFF + ssub[r] * KMIX + col], adj);
            }
          }
        } else {
#pragma unroll
          for (int j = 0; j < 4; j++)
            la[(rt * 16 + rr + j) * KMIX + col] = acc[j];
        }
      }
    }
  }
  __syncthreads();
  if (t < 64) {
    float m = -1e30f;
    for (int k = 0; k < KMIX; k++) m = fmaxf(m, la[t * KMIX + k]);
    float s = 0.0f;
    for (int k = 0; k < KMIX; k++) s += __expf(la[t * KMIX + k] - m);
    lse[t] = m + logf(s);
  }
  __syncthreads();
  {
    const int r = t >> 3;
    if (r0 + r < NEOUT) {
#pragma unroll
      for (int i = 0; i < 3; i++) {
        const int c = (t & 7) + 8 * i;
        if (c < KMIX)
          atomicAdd(&rep[ALPHA_OFF + ssub[r] * KMIX + c], la[r * KMIX + c] - lse[r]);
      }
    }
  }
}

// ---------------- fold 64 replicas into final arrays (coalesced)
__global__ __launch_bounds__(256) void k_red(const float* __restrict__ REP,
                                             float* __restrict__ fin) {
  const int i = blockIdx.x * 256 + threadIdx.x;
  if (i < REP_STRIDE) {
    float s = 0.0f;
    for (int r = 0; r < NREP; r++) s += REP[(size_t)r * REP_STRIDE + i];
    fin[i] = s;
  }
}

// ---------------- final: per-subgraph logsumexp, reduce to scalar
__global__ __launch_bounds__(1024) void k_final(
    const float* __restrict__ fin, float* __restrict__ out) {
  __shared__ float part[1024];
  const int s = threadIdx.x;
  const float* red_loss  = fin + LOSS_OFF;
  const float* red_alpha = fin + ALPHA_OFF;
  const float c = fmaxf(fin[CNT_OFF + s], 1.0f);
  float v[KMIX];
  float m = -1e30f;
  for (int k = 0; k < KMIX; k++) {
    v[k] = -red_loss[s * KMIX + k] + red_alpha[s * KMIX + k] / c;
    m = fmaxf(m, v[k]);
  }
  float sum = 0.0f;
  for (int k = 0; k < KMIX; k++) sum += __expf(v[k] - m);
  part[s] = m + logf(sum);
  __syncthreads();
  for (int st = 512; st > 0; st >>= 1) {
    if (s < st) part[s] += part[s + st];
    __syncthreads();
  }
  if (s == 0) out[0] = -part[0] / (float)NEOUT;
}

extern "C" void kernel_launch(void* const* d_in, const int* in_sizes, int n_in,
                              void* d_out, int out_size, void* d_ws, size_t ws_size,
                              hipStream_t stream) {
  const float* A      = (const float*)d_in[0];
  const int*   edges  = (const int*)d_in[1];
  const int*   attidx = (const int*)d_in[2];
  const int*   nif    = (const int*)d_in[3];
  const int*   cl     = (const int*)d_in[4];
  const int*   nig    = (const int*)d_in[5];
  const float* label  = (const float*)d_in[6];
  const int*   subidx = (const int*)d_in[7];
  const float* Wdec   = (const float*)d_in[8];
  const float* bdec   = (const float*)d_in[9];
  const float* cemb   = (const float*)d_in[10];
  const float* Wm1    = (const float*)d_in[11];
  const float* bm1    = (const float*)d_in[12];
  const float* Wm2    = (const float*)d_in[13];
  const float* bm2    = (const float*)d_in[14];
  const float* Wa1    = (const float*)d_in[15];
  const float* ba1    = (const float*)d_in[16];
  const float* Wa2    = (const float*)d_in[17];
  const float* ba2    = (const float*)d_in[18];
  const float* Wih    = (const float*)d_in[19];
  const float* bih    = (const float*)d_in[20];
  const float* Whh    = (const float*)d_in[21];
  const float* bhh    = (const float*)d_in[22];
  const float* Wt1    = (const float*)d_in[23];
  const float* bt1    = (const float*)d_in[24];
  const float* Wt2    = (const float*)d_in[25];
  const float* bt2    = (const float*)d_in[26];
  const float* Wt3    = (const float*)d_in[27];
  const float* bt3    = (const float*)d_in[28];
  const float* Wha1   = (const float*)d_in[29];
  const float* hba1   = (const float*)d_in[30];
  const float* Wha2   = (const float*)d_in[31];
  const float* hba2   = (const float*)d_in[32];
  const float* Wha3   = (const float*)d_in[33];
  const float* hba3   = (const float*)d_in[34];

  char* ws = (char*)d_ws;
  const size_t SZ_STBF = (size_t)NGNN * DDIM * sizeof(short);     // 12,582,912
  const size_t SZ_MSG  = (size_t)NEDGE * DDIM * sizeof(short);    // 76,800,000
  const size_t SZ_REP  = (size_t)NREP * REP_STRIDE * sizeof(float); // 10.75 MB

  unsigned short* stbf   = (unsigned short*)ws;
  unsigned short* msgbuf = (unsigned short*)(ws + SZ_STBF);
  // overlays inside the msgbuf region (disjoint lifetimes, stream-ordered):
  float* nf  = (float*)(ws + SZ_STBF);            // dec output, dead before edge
  float* REP = (float*)(ws + SZ_STBF);            // used only after last gru
  float* fin = (float*)(ws + SZ_STBF + SZ_REP);

  char* tail = ws + SZ_STBF + SZ_MSG;
  int* rowptr = (int*)tail;                       // (NGNN+1) ints, pad to 131,328
  int* degcur = (int*)(tail + 131328);            // NGNN ints (deg, then cursor)
  int* eidx   = (int*)(tail + 131328 + 131072);   // NEDGE ints = 800,000 B
  short* pk   = (short*)(tail + 131328 + 131072 + 800000);
  short* pWm1  = pk;             // K=320: 10*12*512
  short* pWa1e = pWm1  + 61440;  // K=320: 10*8*512
  short* pWm2  = pWa1e + 40960;  // 6*12*512
  short* pWa2e = pWm2  + 36864;  // 4*12*512
  short* pWt1  = pWa2e + 24576;  // 6*8*512
  short* pWt2  = pWt1  + 24576;  // 4*8*512
  short* pWt3  = pWt2  + 16384;  // 4*2*512
  short* pWh1  = pWt3  + 4096;   // 6*8*512
  short* pWh2  = pWh1  + 24576;  // 4*8*512
  short* pWh3  = pWh2  + 16384;  // 4*2*512
  short* pWih  = pWh3  + 4096;   // 6*36*512
  short* pWhh  = pWih  + 110592; // 6*36*512

  // CSR build by dst (once; edges are constant across props)
  hipMemsetAsync(degcur, 0, (size_t)NGNN * sizeof(int), stream);
  k_hist<<<(NEDGE + 255) / 256, 256, 0, stream>>>(edges, degcur);
  k_scan<<<1, 1024, 0, stream>>>(degcur, rowptr, degcur);
  k_scatter<<<(NEDGE + 255) / 256, 256, 0, stream>>>(edges, degcur, eidx);

  // pack weights to bf16 B-fragment layout (grid = (K/32)*CT)
  k_pack<<<120, 64, 0, stream>>>(Wm1,  pWm1,  192, 12);   // K=320
  k_pack<<< 80, 64, 0, stream>>>(Wa1,  pWa1e, 128, 8);    // K=320
  k_pack<<< 72, 64, 0, stream>>>(Wm2,  pWm2,  192, 12);
  k_pack<<< 48, 64, 0, stream>>>(Wa2,  pWa2e, 192, 12);
  k_pack<<< 48, 64, 0, stream>>>(Wt1,  pWt1,  128, 8);
  k_pack<<< 32, 64, 0, stream>>>(Wt2,  pWt2,  128, 8);
  k_pack<<<  8, 64, 0, stream>>>(Wt3,  pWt3,   20, 2);
  k_pack<<< 48, 64, 0, stream>>>(Wha1, pWh1,  128, 8);
  k_pack<<< 32, 64, 0, stream>>>(Wha2, pWh2,  128, 8);
  k_pack<<<  8, 64, 0, stream>>>(Wha3, pWh3,   20, 2);
  k_pack<<<216, 64, 0, stream>>>(Wih,  pWih,  576, 36);
  k_pack<<<216, 64, 0, stream>>>(Whh,  pWhh,  576, 36);

  k_dec<<<NGNN, 128, 0, stream>>>(A, Wdec, bdec, nf);
  k_state<<<NGNN, 192, 0, stream>>>(nf, cemb, nif, cl, stbf);
  for (int p = 0; p < 2; p++) {
    k_edge_mfma<<<NEDGE / 64, 256, 0, stream>>>(stbf, edges, attidx,
        bm1, pWm1, pWm2, bm2, ba1, pWa1e, pWa2e, ba2, msgbuf);
    k_gru_mfma<<<NGNN / 64, 256, 0, stream>>>(stbf, msgbuf, rowptr, eidx,
        pWih, bih, pWhh, bhh);
  }
  hipMemsetAsync(REP, 0, SZ_REP, stream);
  k_head_mfma<<<(NEOUT + 63) / 64, 512, 0, stream>>>(stbf, nig, label, subidx,
      pWt1, bt1, pWt2, bt2, pWt3, bt3, pWh1, hba1, pWh2, hba2, pWh3, hba3, REP);
  k_red<<<(REP_STRIDE + 255) / 256, 256, 0, stream>>>(REP, fin);
  k_final<<<1, 1024, 0, stream>>>(fin, (float*)d_out);
}

// Round 15
// 837.258 us; speedup vs baseline: 1.4467x; 1.0270x over previous
//
#include <hip/hip_runtime.h>
#include <math.h>

#define NGNN   32768
#define NMAXD  1024
#define HIDD   128
#define CLSD   64
#define DDIM   192
#define ATTH   128
#define NEDGE  200000
#define NEOUT  500000
#define NSUB   1024
#define KMIX   20

#define NREP      64
#define LOSS_OFF  0
#define ALPHA_OFF 20480
#define CNT_OFF   40960
#define REP_STRIDE 41984

typedef __attribute__((ext_vector_type(8))) short bf16x8;
typedef __attribute__((ext_vector_type(8))) unsigned short u16x8;
typedef __attribute__((ext_vector_type(4))) float f32x4;

__device__ __forceinline__ float sigm(float x) { return 1.0f / (1.0f + __expf(-x)); }
__device__ __forceinline__ float tanhf_(float x) { return 2.0f / (1.0f + __expf(-2.0f * x)) - 1.0f; }

__device__ __forceinline__ short f2bf(float f) {
  union { float f; unsigned u; } v; v.f = f;
  unsigned r = v.u + 0x7FFFu + ((v.u >> 16) & 1u);
  return (short)(r >> 16);
}
__device__ __forceinline__ float bf2f(unsigned short u) {
  union { unsigned u; float f; } v; v.u = ((unsigned)u) << 16;
  return v.f;
}
__device__ __forceinline__ f32x4 bc4(float b) {
  f32x4 v; v[0] = b; v[1] = b; v[2] = b; v[3] = b; return v;
}
// bank swizzle on 16B-unit index (bijective involution) — used in HEAD only
__device__ __forceinline__ int swz(int u) { return u ^ ((u >> 4) & 7); }

// ---------------- CSR build (once): histogram by dst, scan, scatter
__global__ __launch_bounds__(256) void k_hist(const int* __restrict__ edges,
                                              int* __restrict__ deg) {
  const int e = blockIdx.x * 256 + threadIdx.x;
  if (e < NEDGE) atomicAdd(&deg[edges[2 * e + 1]], 1);
}

__global__ __launch_bounds__(1024) void k_scan(const int* deg_in,
                                               int* rowptr, int* cursor) {
  __shared__ int part[1024];
  const int t = threadIdx.x;
  const int base = t * 32;
  int loc[32];
  int s = 0;
#pragma unroll
  for (int i = 0; i < 32; i++) { loc[i] = deg_in[base + i]; s += loc[i]; }
  part[t] = s;
  __syncthreads();
  for (int off = 1; off < 1024; off <<= 1) {
    int v = 0;
    if (t >= off) v = part[t - off];
    __syncthreads();
    part[t] += v;
    __syncthreads();
  }
  int pre = (t == 0) ? 0 : part[t - 1];
#pragma unroll
  for (int i = 0; i < 32; i++) {
    rowptr[base + i] = pre;
    cursor[base + i] = pre;
    pre += loc[i];
  }
  if (t == 1023) rowptr[NGNN] = pre;
}

__global__ __launch_bounds__(256) void k_scatter(const int* __restrict__ edges,
                                                 int* __restrict__ cursor,
                                                 int* __restrict__ eidx) {
  const int e = blockIdx.x * 256 + threadIdx.x;
  if (e < NEDGE) {
    const int p = atomicAdd(&cursor[edges[2 * e + 1]], 1);
    eidx[p] = e;
  }
}

// ---------------- merged weight-pack kernel: all 12 matrices + degcur zeroing.
// Pack: out[((ks*CT+ct)*64 + l)*8 + j] = bf16(W[(ks*32+(l>>4)*8+j)][ct*16+(l&15)])
struct PackArgs {
  const float* W[12];
  short* out[12];
  int N[12];
  int CT[12];
  int start[13];   // block-range prefix; start[12] = total pack blocks
  int* deg;        // zero target (NGNN ints), handled by tail blocks
};

__global__ __launch_bounds__(64) void k_pack_all(PackArgs a) {
  const int bid = blockIdx.x;
  const int l = threadIdx.x;
  if (bid >= a.start[12]) {
    // zero degcur: 64 blocks x 64 threads x 8 ints = 32768
    const int base = (bid - a.start[12]) * 512 + l * 8;
#pragma unroll
    for (int j = 0; j < 8; j++) a.deg[base + j] = 0;
    return;
  }
  int m = 0;
  while (bid >= a.start[m + 1]) m++;
  const int lb = bid - a.start[m];
  const int CT = a.CT[m], N = a.N[m];
  const int ks = lb / CT;
  const int ct = lb % CT;
  const float* W = a.W[m];
  short* out = a.out[m];
  const int row0 = ks * 32 + (l >> 4) * 8;
  const int col = ct * 16 + (l & 15);
  short v[8];
#pragma unroll
  for (int j = 0; j < 8; j++) {
    const float f = (col < N) ? W[(size_t)(row0 + j) * N + col] : 0.0f;
    v[j] = f2bf(f);
  }
  *(bf16x8*)(out + ((size_t)lb * 64 + l) * 8) = *(bf16x8*)v;
}

// ---------------- nf = A @ W_dec + b_dec, exploiting A in {0,1} with ~5% density
__global__ __launch_bounds__(128) void k_dec(
    const float* __restrict__ A, const float* __restrict__ Wd,
    const float* __restrict__ bd, float* __restrict__ nf) {
  __shared__ float arow[NMAXD];
  __shared__ int   nz[NMAXD];
  __shared__ int   cnt;
  const int row = blockIdx.x;
  const int t = threadIdx.x;
  if (t == 0) cnt = 0;
  const float4* A4 = (const float4*)(A + (size_t)row * NMAXD);
  float4* a4 = (float4*)arow;
  a4[t] = A4[t];
  a4[t + 128] = A4[t + 128];
  __syncthreads();
  for (int i = t; i < NMAXD; i += 128) {
    if (arow[i] != 0.0f) {
      int p = atomicAdd(&cnt, 1);
      nz[p] = i;
    }
  }
  __syncthreads();
  float acc = bd[t];
  const int n = cnt;
  for (int i = 0; i < n; i++) acc += Wd[(size_t)nz[i] * HIDD + t];
  nf[(size_t)row * HIDD + t] = acc;
}

// ---------------- stbf[i] = bf16(concat(nf[nif[i]] (0-row aware), class_emb[cl[i]]))
__global__ __launch_bounds__(192) void k_state(
    const float* __restrict__ nf, const float* __restrict__ cemb,
    const int* __restrict__ nif, const int* __restrict__ cl,
    unsigned short* __restrict__ stbf) {
  const int i = blockIdx.x;
  const int t = threadIdx.x;
  float v;
  if (t < HIDD) {
    const int idx = nif[i];
    v = (idx == 0) ? 0.0f : nf[(size_t)(idx - 1) * HIDD + t];
  } else {
    v = cemb[cl[i] * CLSD + (t - HIDD)];
  }
  stbf[(size_t)i * DDIM + t] = (unsigned short)f2bf(v);
}

// ---------------- MFMA edge kernel v5 (round-10/14 config, NO swizzle):
// 64 edges/block, 256 threads (4 waves). Outer-product column-split,
// K=320 in-register one-hot, no atomics (msgbuf).
__global__ __launch_bounds__(256, 2) void k_edge_mfma(
    const unsigned short* __restrict__ stbf, const int* __restrict__ edges,
    const int* __restrict__ attidx,
    const float* __restrict__ bm1,
    const short* __restrict__ pWm1, const short* __restrict__ pWm2,
    const float* __restrict__ bm2,
    const float* __restrict__ ba1,
    const short* __restrict__ pWa1, const short* __restrict__ pWa2,
    const float* __restrict__ ba2,
    unsigned short* __restrict__ msgbuf) {
  __shared__ short pdiff[12288];  // [rt<4][ks<6][64][8] 24KB; later msgrow[64][192]
  __shared__ short phm[12288];    // hm A-frags (K=192)  24KB
  __shared__ short pha[8192];     // ha A-frags (K=128)  16KB
  __shared__ int   sa0[64], sa1[64];

  const int t = threadIdx.x;
  const int e0 = blockIdx.x * 64;
  const int wid = t >> 6, l = t & 63;
  const int col16 = l & 15, rr = (l >> 4) * 4;
  const int cb = (l >> 4) * 8;

  if (t < 64) {
    const int s = edges[2 * (e0 + t)];
    const int d = edges[2 * (e0 + t) + 1];
    sa0[t] = attidx[s] + 192;
    sa1[t] = attidx[d] + 256;
  }
  // stage diff A-frags
  for (int it = 0; it < 6; it++) {
    const int id = t + 256 * it;      // 1536 tasks: 64 rows x 24 col-groups
    const int r = id / 24, g24 = id % 24;
    const int e = e0 + r;
    const int s = edges[2 * e], d = edges[2 * e + 1];
    const u16x8 a = *(const u16x8*)&stbf[(size_t)s * DDIM + g24 * 8];
    const u16x8 b = *(const u16x8*)&stbf[(size_t)d * DDIM + g24 * 8];
    short v[8];
#pragma unroll
    for (int j = 0; j < 8; j++) v[j] = f2bf(bf2f(a[j]) - bf2f(b[j]));
    const int rt = r >> 4, ks = g24 >> 2, g = g24 & 3;
    *(bf16x8*)&pdiff[((rt * 6 + ks) * 64 + g * 16 + (r & 15)) * 8] = *(bf16x8*)v;
  }
  __syncthreads();

  // per-lane one-hot targets for row (l&15) of each row-tile
  int a0v[4], a1v[4];
#pragma unroll
  for (int rt = 0; rt < 4; rt++) {
    a0v[rt] = sa0[rt * 16 + (l & 15)];
    a1v[rt] = sa1[rt * 16 + (l & 15)];
  }

  const int w5 = wid * 5;

  // ---- L1: [64x320] @ [320x(192|128)] fused, ks-outer outer-product ----
  {
    f32x4 acc[5][4];
#pragma unroll
    for (int u = 0; u < 5; u++)
#pragma unroll
      for (int rt = 0; rt < 4; rt++) acc[u][rt] = bc4(0.0f);

    for (int ks = 0; ks < 10; ks++) {
      bf16x8 A[4];
      if (ks < 6) {
#pragma unroll
        for (int rt = 0; rt < 4; rt++)
          A[rt] = *(const bf16x8*)&pdiff[((rt * 6 + ks) * 64 + l) * 8];
      } else {
        const int kb = ks * 32 + cb;
#pragma unroll
        for (int rt = 0; rt < 4; rt++) {
          short v[8];
#pragma unroll
          for (int j = 0; j < 8; j++) {
            const int kg = kb + j;
            v[j] = (kg == a0v[rt] || kg == a1v[rt]) ? (short)0x3F80 : (short)0;
          }
          A[rt] = *(bf16x8*)v;
        }
      }
      bf16x8 B[5];
#pragma unroll
      for (int u = 0; u < 5; u++) {
        const int unit = w5 + u;
        const short* bp = (unit < 12)
            ? &pWm1[((ks * 12 + unit) * 64 + l) * 8]
            : &pWa1[((ks * 8 + (unit - 12)) * 64 + l) * 8];
        B[u] = *(const bf16x8*)bp;
      }
#pragma unroll
      for (int u = 0; u < 5; u++)
#pragma unroll
        for (int rt = 0; rt < 4; rt++)
          acc[u][rt] = __builtin_amdgcn_mfma_f32_16x16x32_bf16(A[rt], B[u], acc[u][rt], 0, 0, 0);
    }

    // bias + relu + relayout to phm/pha
#pragma unroll
    for (int u = 0; u < 5; u++) {
      const int unit = w5 + u;
      const int isMsg = (unit < 12);
      const int ct = isMsg ? unit : unit - 12;
      const int col = ct * 16 + col16;
      const float bb = isMsg ? bm1[col] : ba1[col];
      const int ksp = col >> 5, gp = (col & 31) >> 3, jp = col & 7;
#pragma unroll
      for (int rt = 0; rt < 4; rt++)
#pragma unroll
        for (int j = 0; j < 4; j++) {
          const short hv = f2bf(fmaxf(acc[u][rt][j] + bb, 0.0f));
          if (isMsg) phm[((rt * 6 + ksp) * 64 + gp * 16 + rr + j) * 8 + jp] = hv;
          else       pha[((rt * 4 + ksp) * 64 + gp * 16 + rr + j) * 8 + jp] = hv;
        }
    }
  }
  __syncthreads();

  // ---- L2: wave owns 3 of 12 output cts x 4 rts ----
  {
    const int w3 = wid * 3;
    f32x4 m[3][4], av[3][4];
#pragma unroll
    for (int c = 0; c < 3; c++) {
      const int col = (w3 + c) * 16 + col16;
      const f32x4 bm = bc4(bm2[col]), ba = bc4(ba2[col]);
#pragma unroll
      for (int rt = 0; rt < 4; rt++) { m[c][rt] = bm; av[c][rt] = ba; }
    }
    for (int ks = 0; ks < 6; ks++) {
      bf16x8 A[4];
#pragma unroll
      for (int rt = 0; rt < 4; rt++)
        A[rt] = *(const bf16x8*)&phm[((rt * 6 + ks) * 64 + l) * 8];
      bf16x8 B[3];
#pragma unroll
      for (int c = 0; c < 3; c++)
        B[c] = *(const bf16x8*)&pWm2[((ks * 12 + w3 + c) * 64 + l) * 8];
#pragma unroll
      for (int c = 0; c < 3; c++)
#pragma unroll
        for (int rt = 0; rt < 4; rt++)
          m[c][rt] = __builtin_amdgcn_mfma_f32_16x16x32_bf16(A[rt], B[c], m[c][rt], 0, 0, 0);
    }
    for (int ks = 0; ks < 4; ks++) {
      bf16x8 A[4];
#pragma unroll
      for (int rt = 0; rt < 4; rt++)
        A[rt] = *(const bf16x8*)&pha[((rt * 4 + ks) * 64 + l) * 8];
      bf16x8 B[3];
#pragma unroll
      for (int c = 0; c < 3; c++)
        B[c] = *(const bf16x8*)&pWa2[((ks * 12 + w3 + c) * 64 + l) * 8];
#pragma unroll
      for (int c = 0; c < 3; c++)
#pragma unroll
        for (int rt = 0; rt < 4; rt++)
          av[c][rt] = __builtin_amdgcn_mfma_f32_16x16x32_bf16(A[rt], B[c], av[c][rt], 0, 0, 0);
    }

    // write combined values to LDS msgrow (overlays pdiff; dead since L1 + barrier)
    short* msgrow = pdiff;
#pragma unroll
    for (int c = 0; c < 3; c++) {
      const int col = (w3 + c) * 16 + col16;
#pragma unroll
      for (int rt = 0; rt < 4; rt++)
#pragma unroll
        for (int j = 0; j < 4; j++)
          msgrow[(rt * 16 + rr + j) * DDIM + col] = f2bf(m[c][rt][j] * sigm(av[c][rt][j]));
    }
  }
  __syncthreads();

  // coalesced copy msgrow -> msgbuf (64 rows x 384B)
  {
    const short* msgrow = pdiff;
    for (int it = 0; it < 6; it++) {
      const int id = t + 256 * it;      // 1536 tasks
      const int r = id / 24, g = id % 24;
      *(float4*)&msgbuf[(size_t)(e0 + r) * DDIM + g * 8] =
          *(const float4*)&msgrow[r * DDIM + g * 8];
    }
  }
}

// ---------------- MFMA GRU: 64 nodes/block, 256 threads (4 waves), zero LDS.
__global__ __launch_bounds__(256, 2) void k_gru_mfma(
    unsigned short* __restrict__ stbf,
    const unsigned short* __restrict__ msgbuf,
    const int* __restrict__ rowptr, const int* __restrict__ eidx,
    const short* __restrict__ pWih, const float* __restrict__ bih,
    const short* __restrict__ pWhh, const float* __restrict__ bhh) {
  const int t = threadIdx.x;
  const int n0 = blockIdx.x * 64;
  const int wid = t >> 6, l = t & 63;
  const int col16 = l & 15, rr = (l >> 4) * 4;
  const int cb = (l >> 4) * 8;
  const int row = n0 + wid * 16 + (l & 15);

  float afacc[6][8];
#pragma unroll
  for (int ks = 0; ks < 6; ks++)
#pragma unroll
    for (int j = 0; j < 8; j++) afacc[ks][j] = 0.0f;

  const int rbeg = rowptr[row], rend = rowptr[row + 1];
  for (int p = rbeg; p < rend; p++) {
    const int e = eidx[p];
    const unsigned short* mr = &msgbuf[(size_t)e * DDIM + cb];
#pragma unroll
    for (int ks = 0; ks < 6; ks++) {
      const u16x8 cc = *(const u16x8*)(mr + ks * 32);
#pragma unroll
      for (int j = 0; j < 8; j++) afacc[ks][j] += bf2f(cc[j]);
    }
  }

  bf16x8 af[6], sf[6];
#pragma unroll
  for (int ks = 0; ks < 6; ks++) {
    short v[8];
#pragma unroll
    for (int j = 0; j < 8; j++) v[j] = f2bf(afacc[ks][j]);
    af[ks] = *(bf16x8*)v;
    sf[ks] = *(const bf16x8*)&stbf[(size_t)row * DDIM + ks * 32 + cb];
  }

  for (int ct = 0; ct < 12; ct++) {
    const int c = ct * 16 + col16;
    f32x4 ir = bc4(bih[c]), iz = bc4(bih[c + DDIM]), in_ = bc4(bih[c + 2 * DDIM]);
    f32x4 hr = bc4(bhh[c]), hz = bc4(bhh[c + DDIM]), hn = bc4(bhh[c + 2 * DDIM]);
#pragma unroll
    for (int ks = 0; ks < 6; ks++) {
      const bf16x8 wr = *(const bf16x8*)&pWih[((size_t)(ks * 36 + ct) * 64 + l) * 8];
      const bf16x8 wz = *(const bf16x8*)&pWih[((size_t)(ks * 36 + ct + 12) * 64 + l) * 8];
      const bf16x8 wn = *(const bf16x8*)&pWih[((size_t)(ks * 36 + ct + 24) * 64 + l) * 8];
      ir  = __builtin_amdgcn_mfma_f32_16x16x32_bf16(af[ks], wr, ir, 0, 0, 0);
      iz  = __builtin_amdgcn_mfma_f32_16x16x32_bf16(af[ks], wz, iz, 0, 0, 0);
      in_ = __builtin_amdgcn_mfma_f32_16x16x32_bf16(af[ks], wn, in_, 0, 0, 0);
      const bf16x8 vr = *(const bf16x8*)&pWhh[((size_t)(ks * 36 + ct) * 64 + l) * 8];
      const bf16x8 vz = *(const bf16x8*)&pWhh[((size_t)(ks * 36 + ct + 12) * 64 + l) * 8];
      const bf16x8 vn = *(const bf16x8*)&pWhh[((size_t)(ks * 36 + ct + 24) * 64 + l) * 8];
      hr = __builtin_amdgcn_mfma_f32_16x16x32_bf16(sf[ks], vr, hr, 0, 0, 0);
      hz = __builtin_amdgcn_mfma_f32_16x16x32_bf16(sf[ks], vz, hz, 0, 0, 0);
      hn = __builtin_amdgcn_mfma_f32_16x16x32_bf16(sf[ks], vn, hn, 0, 0, 0);
    }
#pragma unroll
    for (int j = 0; j < 4; j++) {
      const size_t idx = (size_t)(n0 + wid * 16 + rr + j) * DDIM + c;
      const float sv = bf2f(stbf[idx]);
      const float r = sigm(ir[j] + hr[j]);
      const float z = sigm(iz[j] + hz[j]);
      const float nn = tanhf_(in_[j] + r * hn[j]);
      stbf[idx] = (unsigned short)f2bf((1.0f - z) * nn + z * sv);
    }
  }
}

// ---------------- MFMA head v3 + swizzle (round-11/14 config): 64 rows/block,
// 512 threads (8 waves). Wave = (branch b, col-pair cw).
__global__ __launch_bounds__(512, 4) void k_head_mfma(
    const unsigned short* __restrict__ stbf, const int* __restrict__ nig,
    const float* __restrict__ label, const int* __restrict__ subidx,
    const short* __restrict__ pWt1, const float* __restrict__ bt1,
    const short* __restrict__ pWt2, const float* __restrict__ bt2,
    const short* __restrict__ pWt3, const float* __restrict__ bt3,
    const short* __restrict__ pWa1, const float* __restrict__ ba1,
    const short* __restrict__ pWa2, const float* __restrict__ ba2,
    const short* __restrict__ pWa3, const float* __restrict__ ba3,
    float* __restrict__ REP) {
  __shared__ short u1[16384];    // pd [rt<4][ks<6][64][8] (24KB) / ph2 t+a (16+16KB)
  __shared__ short ph1[16384];   // ph1t + ph1a, each [rt<4][ks<4][64][8]
  __shared__ float la[64 * KMIX];
  __shared__ int   ssub[64];
  __shared__ float slab[64];
  __shared__ float lse[64];

  const int t = threadIdx.x;
  const int r0 = blockIdx.x * 64;
  float* rep = REP + (size_t)(blockIdx.x & (NREP - 1)) * REP_STRIDE;

  if (t < 64) {
    const int gr = r0 + t;
    const int sb = (gr < NEOUT) ? subidx[gr] : 0;
    ssub[t] = sb;
    slab[t] = (gr < NEOUT) ? label[gr] : 0.0f;
    if (gr < NEOUT) atomicAdd(&rep[CNT_OFF + sb], 1.0f);
  }

  // stage diff A-frags into pd (u1), swizzled
  for (int it = 0; it < 3; it++) {
    const int id = t + 512 * it;      // 1536 tasks: 64 rows x 24 col-groups
    const int r = id / 24, g24 = id % 24;
    const int gr = r0 + r;
    const int ok = (gr < NEOUT);
    const int ia = ok ? nig[2 * gr] : 0;
    const int ib = ok ? nig[2 * gr + 1] : 0;   // ia==ib -> zero diff on pad rows
    const u16x8 a = *(const u16x8*)&stbf[(size_t)ia * DDIM + g24 * 8];
    const u16x8 b = *(const u16x8*)&stbf[(size_t)ib * DDIM + g24 * 8];
    short v[8];
#pragma unroll
    for (int j = 0; j < 8; j++) v[j] = f2bf(bf2f(a[j]) - bf2f(b[j]));
    const int rt = r >> 4, ks = g24 >> 2, g = g24 & 3;
    *(bf16x8*)&u1[swz((rt * 6 + ks) * 64 + g * 16 + (r & 15)) * 8] = *(bf16x8*)v;
  }
  __syncthreads();

  const int wid = t >> 6, l = t & 63;
  const int b = wid >> 2, cw = wid & 3;
  const int col16 = l & 15, rr = (l >> 4) * 4;

  const short* pW1 = b ? pWa1 : pWt1;
  const short* pW2 = b ? pWa2 : pWt2;
  const short* pW3 = b ? pWa3 : pWt3;
  const float* bv1 = b ? ba1 : bt1;
  const float* bv2 = b ? ba2 : bt2;
  const float* bv3 = b ? ba3 : bt3;
  short* ph1b = ph1 + b * 8192;
  short* ph2b = u1 + b * 8192;

  // ---- L1: K=192, this wave's 2 cts; B persistent in regs ----
  {
    bf16x8 B1[12];
    float bias[2];
#pragma unroll
    for (int c2 = 0; c2 < 2; c2++) {
      const int ct = cw * 2 + c2;
      bias[c2] = bv1[ct * 16 + col16];
#pragma unroll
      for (int ks = 0; ks < 6; ks++)
        B1[c2 * 6 + ks] = *(const bf16x8*)&pW1[((ks * 8 + ct) * 64 + l) * 8];
    }
    for (int rt = 0; rt < 4; rt++) {
      bf16x8 a[6];
#pragma unroll
      for (int ks = 0; ks < 6; ks++)
        a[ks] = *(const bf16x8*)&u1[swz((rt * 6 + ks) * 64 + l) * 8];
      f32x4 acc0 = bc4(bias[0]), acc1 = bc4(bias[1]);
#pragma unroll
      for (int ks = 0; ks < 6; ks++) {
        acc0 = __builtin_amdgcn_mfma_f32_16x16x32_bf16(a[ks], B1[ks], acc0, 0, 0, 0);
        acc1 = __builtin_amdgcn_mfma_f32_16x16x32_bf16(a[ks], B1[6 + ks], acc1, 0, 0, 0);
      }
#pragma unroll
      for (int c2 = 0; c2 < 2; c2++) {
        const int col = (cw * 2 + c2) * 16 + col16;
        const int ksp = col >> 5, gp = (col & 31) >> 3, jp = col & 7;
        const f32x4 acc = c2 ? acc1 : acc0;
#pragma unroll
        for (int j = 0; j < 4; j++)
          ph1b[swz((rt * 4 + ksp) * 64 + gp * 16 + rr + j) * 8 + jp] = f2bf(fmaxf(acc[j], 0.0f));
      }
    }
  }
  __syncthreads();   // pd dead; ph1 complete

  // ---- L2: K=128 ----
  {
    bf16x8 B2[8];
    float bias[2];
#pragma unroll
    for (int c2 = 0; c2 < 2; c2++) {
      const int ct = cw * 2 + c2;
      bias[c2] = bv2[ct * 16 + col16];
#pragma unroll
      for (int ks = 0; ks < 4; ks++)
        B2[c2 * 4 + ks] = *(const bf16x8*)&pW2[((ks * 8 + ct) * 64 + l) * 8];
    }
    for (int rt = 0; rt < 4; rt++) {
      bf16x8 a[4];
#pragma unroll
      for (int ks = 0; ks < 4; ks++)
        a[ks] = *(const bf16x8*)&ph1b[swz((rt * 4 + ks) * 64 + l) * 8];
      f32x4 acc0 = bc4(bias[0]), acc1 = bc4(bias[1]);
#pragma unroll
      for (int ks = 0; ks < 4; ks++) {
        acc0 = __builtin_amdgcn_mfma_f32_16x16x32_bf16(a[ks], B2[ks], acc0, 0, 0, 0);
        acc1 = __builtin_amdgcn_mfma_f32_16x16x32_bf16(a[ks], B2[4 + ks], acc1, 0, 0, 0);
      }
#pragma unroll
      for (int c2 = 0; c2 < 2; c2++) {
        const int col = (cw * 2 + c2) * 16 + col16;
        const int ksp = col >> 5, gp = (col & 31) >> 3, jp = col & 7;
        const f32x4 acc = c2 ? acc1 : acc0;
#pragma unroll
        for (int j = 0; j < 4; j++)
          ph2b[swz((rt * 4 + ksp) * 64 + gp * 16 + rr + j) * 8 + jp] = f2bf(fmaxf(acc[j], 0.0f));
      }
    }
  }
  __syncthreads();

  // ---- L3: K=128, N=32 (cols>=20 zero-padded) ----
  {
    const int ct3 = cw & 1, rth = cw >> 1;
    const int col = ct3 * 16 + col16;
    bf16x8 B3[4];
#pragma unroll
    for (int ks = 0; ks < 4; ks++)
      B3[ks] = *(const bf16x8*)&pW3[((ks * 2 + ct3) * 64 + l) * 8];
    const float bias = (col < KMIX) ? bv3[col] : 0.0f;
#pragma unroll
    for (int i = 0; i < 2; i++) {
      const int rt = rth * 2 + i;
      bf16x8 a[4];
#pragma unroll
      for (int ks = 0; ks < 4; ks++)
        a[ks] = *(const bf16x8*)&ph2b[swz((rt * 4 + ks) * 64 + l) * 8];
      f32x4 acc = bc4(bias);
#pragma unroll
      for (int ks = 0; ks < 4; ks++)
        acc = __builtin_amdgcn_mfma_f32_16x16x32_bf16(a[ks], B3[ks], acc, 0, 0, 0);
      if (col < KMIX) {
        if (b == 0) {
#pragma unroll
          for (int j = 0; j < 4; j++) {
            const int r = rt * 16 + rr + j;
            if (r0 + r < NEOUT) {
              const float lt = acc[j];
              const float adj = fmaxf(lt, 0.0f) + logf(1.0f + __expf(-fabsf(lt))) - lt * slab[r];
              atomicAdd(&rep[LOSS_OFF + ssub[r] * KMIX + col], adj);
            }
          }
        } else {
#pragma unroll
          for (int j = 0; j < 4; j++)
            la[(rt * 16 + rr + j) * KMIX + col] = acc[j];
        }
      }
    }
  }
  __syncthreads();
  if (t < 64) {
    float m = -1e30f;
    for (int k = 0; k < KMIX; k++) m = fmaxf(m, la[t * KMIX + k]);
    float s = 0.0f;
    for (int k = 0; k < KMIX; k++) s += __expf(la[t * KMIX + k] - m);
    lse[t] = m + logf(s);
  }
  __syncthreads();
  {
    const int r = t >> 3;
    if (r0 + r < NEOUT) {
#pragma unroll
      for (int i = 0; i < 3; i++) {
        const int c = (t & 7) + 8 * i;
        if (c < KMIX)
          atomicAdd(&rep[ALPHA_OFF + ssub[r] * KMIX + c], la[r * KMIX + c] - lse[r]);
      }
    }
  }
}

// ---------------- fold 64 replicas into final arrays (coalesced)
__global__ __launch_bounds__(256) void k_red(const float* __restrict__ REP,
                                             float* __restrict__ fin) {
  const int i = blockIdx.x * 256 + threadIdx.x;
  if (i < REP_STRIDE) {
    float s = 0.0f;
    for (int r = 0; r < NREP; r++) s += REP[(size_t)r * REP_STRIDE + i];
    fin[i] = s;
  }
}

// ---------------- final: per-subgraph logsumexp, reduce to scalar
__global__ __launch_bounds__(1024) void k_final(
    const float* __restrict__ fin, float* __restrict__ out) {
  __shared__ float part[1024];
  const int s = threadIdx.x;
  const float* red_loss  = fin + LOSS_OFF;
  const float* red_alpha = fin + ALPHA_OFF;
  const float c = fmaxf(fin[CNT_OFF + s], 1.0f);
  float v[KMIX];
  float m = -1e30f;
  for (int k = 0; k < KMIX; k++) {
    v[k] = -red_loss[s * KMIX + k] + red_alpha[s * KMIX + k] / c;
    m = fmaxf(m, v[k]);
  }
  float sum = 0.0f;
  for (int k = 0; k < KMIX; k++) sum += __expf(v[k] - m);
  part[s] = m + logf(sum);
  __syncthreads();
  for (int st = 512; st > 0; st >>= 1) {
    if (s < st) part[s] += part[s + st];
    __syncthreads();
  }
  if (s == 0) out[0] = -part[0] / (float)NEOUT;
}

extern "C" void kernel_launch(void* const* d_in, const int* in_sizes, int n_in,
                              void* d_out, int out_size, void* d_ws, size_t ws_size,
                              hipStream_t stream) {
  const float* A      = (const float*)d_in[0];
  const int*   edges  = (const int*)d_in[1];
  const int*   attidx = (const int*)d_in[2];
  const int*   nif    = (const int*)d_in[3];
  const int*   cl     = (const int*)d_in[4];
  const int*   nig    = (const int*)d_in[5];
  const float* label  = (const float*)d_in[6];
  const int*   subidx = (const int*)d_in[7];
  const float* Wdec   = (const float*)d_in[8];
  const float* bdec   = (const float*)d_in[9];
  const float* cemb   = (const float*)d_in[10];
  const float* Wm1    = (const float*)d_in[11];
  const float* bm1    = (const float*)d_in[12];
  const float* Wm2    = (const float*)d_in[13];
  const float* bm2    = (const float*)d_in[14];
  const float* Wa1    = (const float*)d_in[15];
  const float* ba1    = (const float*)d_in[16];
  const float* Wa2    = (const float*)d_in[17];
  const float* ba2    = (const float*)d_in[18];
  const float* Wih    = (const float*)d_in[19];
  const float* bih    = (const float*)d_in[20];
  const float* Whh    = (const float*)d_in[21];
  const float* bhh    = (const float*)d_in[22];
  const float* Wt1    = (const float*)d_in[23];
  const float* bt1    = (const float*)d_in[24];
  const float* Wt2    = (const float*)d_in[25];
  const float* bt2    = (const float*)d_in[26];
  const float* Wt3    = (const float*)d_in[27];
  const float* bt3    = (const float*)d_in[28];
  const float* Wha1   = (const float*)d_in[29];
  const float* hba1   = (const float*)d_in[30];
  const float* Wha2   = (const float*)d_in[31];
  const float* hba2   = (const float*)d_in[32];
  const float* Wha3   = (const float*)d_in[33];
  const float* hba3   = (const float*)d_in[34];

  char* ws = (char*)d_ws;
  const size_t SZ_STBF = (size_t)NGNN * DDIM * sizeof(short);     // 12,582,912
  const size_t SZ_MSG  = (size_t)NEDGE * DDIM * sizeof(short);    // 76,800,000
  const size_t SZ_REP  = (size_t)NREP * REP_STRIDE * sizeof(float); // 10.75 MB

  unsigned short* stbf   = (unsigned short*)ws;
  unsigned short* msgbuf = (unsigned short*)(ws + SZ_STBF);
  // overlays inside the msgbuf region (disjoint lifetimes, stream-ordered):
  float* nf  = (float*)(ws + SZ_STBF);            // dec output, dead before edge
  float* REP = (float*)(ws + SZ_STBF);            // used only after last gru
  float* fin = (float*)(ws + SZ_STBF + SZ_REP);

  char* tail = ws + SZ_STBF + SZ_MSG;
  int* rowptr = (int*)tail;                       // (NGNN+1) ints, pad to 131,328
  int* degcur = (int*)(tail + 131328);            // NGNN ints (deg, then cursor)
  int* eidx   = (int*)(tail + 131328 + 131072);   // NEDGE ints = 800,000 B
  short* pk   = (short*)(tail + 131328 + 131072 + 800000);
  short* pWm1  = pk;             // K=320: 10*12*512
  short* pWa1e = pWm1  + 61440;  // K=320: 10*8*512
  short* pWm2  = pWa1e + 40960;  // 6*12*512
  short* pWa2e = pWm2  + 36864;  // 4*12*512
  short* pWt1  = pWa2e + 24576;  // 6*8*512
  short* pWt2  = pWt1  + 24576;  // 4*8*512
  short* pWt3  = pWt2  + 16384;  // 4*2*512
  short* pWh1  = pWt3  + 4096;   // 6*8*512
  short* pWh2  = pWh1  + 24576;  // 4*8*512
  short* pWh3  = pWh2  + 16384;  // 4*2*512
  short* pWih  = pWh3  + 4096;   // 6*36*512
  short* pWhh  = pWih  + 110592; // 6*36*512

  // merged pack (all 12 weights) + degcur zeroing in one launch
  PackArgs pa;
  const float* srcs[12] = {Wm1, Wa1, Wm2, Wa2, Wt1, Wt2, Wt3, Wha1, Wha2, Wha3, Wih, Whh};
  short* dsts[12] = {pWm1, pWa1e, pWm2, pWa2e, pWt1, pWt2, pWt3, pWh1, pWh2, pWh3, pWih, pWhh};
  const int Ns[12]  = {192, 128, 192, 192, 128, 128, 20, 128, 128, 20, 576, 576};
  const int CTs[12] = {12, 8, 12, 12, 8, 8, 2, 8, 8, 2, 36, 36};
  const int KSs[12] = {10, 10, 6, 4, 6, 4, 4, 6, 4, 4, 6, 6};
  int acc = 0;
  for (int m = 0; m < 12; m++) {
    pa.W[m] = srcs[m]; pa.out[m] = dsts[m]; pa.N[m] = Ns[m]; pa.CT[m] = CTs[m];
    pa.start[m] = acc;
    acc += KSs[m] * CTs[m];
  }
  pa.start[12] = acc;            // 928 pack blocks
  pa.deg = degcur;
  k_pack_all<<<acc + 64, 64, 0, stream>>>(pa);   // +64 zeroing blocks

  // CSR build by dst (once; edges are constant across props)
  k_hist<<<(NEDGE + 255) / 256, 256, 0, stream>>>(edges, degcur);
  k_scan<<<1, 1024, 0, stream>>>(degcur, rowptr, degcur);
  k_scatter<<<(NEDGE + 255) / 256, 256, 0, stream>>>(edges, degcur, eidx);

  k_dec<<<NGNN, 128, 0, stream>>>(A, Wdec, bdec, nf);
  k_state<<<NGNN, 192, 0, stream>>>(nf, cemb, nif, cl, stbf);
  for (int p = 0; p < 2; p++) {
    k_edge_mfma<<<NEDGE / 64, 256, 0, stream>>>(stbf, edges, attidx,
        bm1, pWm1, pWm2, bm2, ba1, pWa1e, pWa2e, ba2, msgbuf);
    k_gru_mfma<<<NGNN / 64, 256, 0, stream>>>(stbf, msgbuf, rowptr, eidx,
        pWih, bih, pWhh, bhh);
  }
  hipMemsetAsync(REP, 0, SZ_REP, stream);
  k_head_mfma<<<(NEOUT + 63) / 64, 512, 0, stream>>>(stbf, nig, label, subidx,
      pWt1, bt1, pWt2, bt2, pWt3, bt3, pWh1, hba1, pWh2, hba2, pWh3, hba3, REP);
  k_red<<<(REP_STRIDE + 255) / 256, 256, 0, stream>>>(REP, fin);
  k_final<<<1, 1024, 0, stream>>>(fin, (float*)d_out);
}

// Round 16
// 835.867 us; speedup vs baseline: 1.4491x; 1.0017x over previous
//
#include <hip/hip_runtime.h>
#include <hip/hip_bf16.h>
#include <math.h>

#define NGNN   32768
#define NMAXD  1024
#define HIDD   128
#define CLSD   64
#define DDIM   192
#define ATTH   128
#define NEDGE  200000
#define NEOUT  500000
#define NSUB   1024
#define KMIX   20

#define NREP      64
#define LOSS_OFF  0
#define ALPHA_OFF 20480
#define CNT_OFF   40960
#define REP_STRIDE 41984

typedef __attribute__((ext_vector_type(8))) short bf16x8;
typedef __attribute__((ext_vector_type(8))) unsigned short u16x8;
typedef __attribute__((ext_vector_type(4))) float f32x4;

__device__ __forceinline__ float sigm(float x) { return 1.0f / (1.0f + __expf(-x)); }
__device__ __forceinline__ float tanhf_(float x) { return 2.0f / (1.0f + __expf(-2.0f * x)) - 1.0f; }

// compiler-native f32->bf16 (RNE): lets hipcc emit v_cvt_pk_bf16_f32 and
// schedule it freely (round-12 inline-asm variant blocked scheduling; this
// form per guide m240 is what the compiler optimizes itself).
__device__ __forceinline__ short f2bf(float f) {
  __hip_bfloat16 h = __float2bfloat16(f);
  return *reinterpret_cast<short*>(&h);
}
__device__ __forceinline__ float bf2f(unsigned short u) {
  union { unsigned u; float f; } v; v.u = ((unsigned)u) << 16;
  return v.f;
}
__device__ __forceinline__ f32x4 bc4(float b) {
  f32x4 v; v[0] = b; v[1] = b; v[2] = b; v[3] = b; return v;
}
// bank swizzle on 16B-unit index (bijective involution) — used in HEAD only
__device__ __forceinline__ int swz(int u) { return u ^ ((u >> 4) & 7); }

// ---------------- CSR build (once): histogram by dst, scan, scatter
__global__ __launch_bounds__(256) void k_hist(const int* __restrict__ edges,
                                              int* __restrict__ deg) {
  const int e = blockIdx.x * 256 + threadIdx.x;
  if (e < NEDGE) atomicAdd(&deg[edges[2 * e + 1]], 1);
}

__global__ __launch_bounds__(1024) void k_scan(const int* deg_in,
                                               int* rowptr, int* cursor) {
  __shared__ int part[1024];
  const int t = threadIdx.x;
  const int base = t * 32;
  int loc[32];
  int s = 0;
#pragma unroll
  for (int i = 0; i < 32; i++) { loc[i] = deg_in[base + i]; s += loc[i]; }
  part[t] = s;
  __syncthreads();
  for (int off = 1; off < 1024; off <<= 1) {
    int v = 0;
    if (t >= off) v = part[t - off];
    __syncthreads();
    part[t] += v;
    __syncthreads();
  }
  int pre = (t == 0) ? 0 : part[t - 1];
#pragma unroll
  for (int i = 0; i < 32; i++) {
    rowptr[base + i] = pre;
    cursor[base + i] = pre;
    pre += loc[i];
  }
  if (t == 1023) rowptr[NGNN] = pre;
}

__global__ __launch_bounds__(256) void k_scatter(const int* __restrict__ edges,
                                                 int* __restrict__ cursor,
                                                 int* __restrict__ eidx) {
  const int e = blockIdx.x * 256 + threadIdx.x;
  if (e < NEDGE) {
    const int p = atomicAdd(&cursor[edges[2 * e + 1]], 1);
    eidx[p] = e;
  }
}

// ---------------- merged weight-pack kernel: all 12 matrices + degcur zeroing.
struct PackArgs {
  const float* W[12];
  short* out[12];
  int N[12];
  int CT[12];
  int start[13];   // block-range prefix; start[12] = total pack blocks
  int* deg;        // zero target (NGNN ints), handled by tail blocks
};

__global__ __launch_bounds__(64) void k_pack_all(PackArgs a) {
  const int bid = blockIdx.x;
  const int l = threadIdx.x;
  if (bid >= a.start[12]) {
    const int base = (bid - a.start[12]) * 512 + l * 8;
#pragma unroll
    for (int j = 0; j < 8; j++) a.deg[base + j] = 0;
    return;
  }
  int m = 0;
  while (bid >= a.start[m + 1]) m++;
  const int lb = bid - a.start[m];
  const int CT = a.CT[m], N = a.N[m];
  const int ks = lb / CT;
  const int ct = lb % CT;
  const float* W = a.W[m];
  short* out = a.out[m];
  const int row0 = ks * 32 + (l >> 4) * 8;
  const int col = ct * 16 + (l & 15);
  short v[8];
#pragma unroll
  for (int j = 0; j < 8; j++) {
    const float f = (col < N) ? W[(size_t)(row0 + j) * N + col] : 0.0f;
    v[j] = f2bf(f);
  }
  *(bf16x8*)(out + ((size_t)lb * 64 + l) * 8) = *(bf16x8*)v;
}

// ---------------- nf = A @ W_dec + b_dec, exploiting A in {0,1} with ~5% density
__global__ __launch_bounds__(128) void k_dec(
    const float* __restrict__ A, const float* __restrict__ Wd,
    const float* __restrict__ bd, float* __restrict__ nf) {
  __shared__ float arow[NMAXD];
  __shared__ int   nz[NMAXD];
  __shared__ int   cnt;
  const int row = blockIdx.x;
  const int t = threadIdx.x;
  if (t == 0) cnt = 0;
  const float4* A4 = (const float4*)(A + (size_t)row * NMAXD);
  float4* a4 = (float4*)arow;
  a4[t] = A4[t];
  a4[t + 128] = A4[t + 128];
  __syncthreads();
  for (int i = t; i < NMAXD; i += 128) {
    if (arow[i] != 0.0f) {
      int p = atomicAdd(&cnt, 1);
      nz[p] = i;
    }
  }
  __syncthreads();
  float acc = bd[t];
  const int n = cnt;
  for (int i = 0; i < n; i++) acc += Wd[(size_t)nz[i] * HIDD + t];
  nf[(size_t)row * HIDD + t] = acc;
}

// ---------------- stbf[i] = bf16(concat(nf[nif[i]] (0-row aware), class_emb[cl[i]]))
__global__ __launch_bounds__(192) void k_state(
    const float* __restrict__ nf, const float* __restrict__ cemb,
    const int* __restrict__ nif, const int* __restrict__ cl,
    unsigned short* __restrict__ stbf) {
  const int i = blockIdx.x;
  const int t = threadIdx.x;
  float v;
  if (t < HIDD) {
    const int idx = nif[i];
    v = (idx == 0) ? 0.0f : nf[(size_t)(idx - 1) * HIDD + t];
  } else {
    v = cemb[cl[i] * CLSD + (t - HIDD)];
  }
  stbf[(size_t)i * DDIM + t] = (unsigned short)f2bf(v);
}

// ---------------- MFMA edge kernel v5 (NO swizzle): 64 edges/block, 256 threads.
__global__ __launch_bounds__(256, 2) void k_edge_mfma(
    const unsigned short* __restrict__ stbf, const int* __restrict__ edges,
    const int* __restrict__ attidx,
    const float* __restrict__ bm1,
    const short* __restrict__ pWm1, const short* __restrict__ pWm2,
    const float* __restrict__ bm2,
    const float* __restrict__ ba1,
    const short* __restrict__ pWa1, const short* __restrict__ pWa2,
    const float* __restrict__ ba2,
    unsigned short* __restrict__ msgbuf) {
  __shared__ short pdiff[12288];  // [rt<4][ks<6][64][8] 24KB; later msgrow[64][192]
  __shared__ short phm[12288];    // hm A-frags (K=192)  24KB
  __shared__ short pha[8192];     // ha A-frags (K=128)  16KB
  __shared__ int   sa0[64], sa1[64];

  const int t = threadIdx.x;
  const int e0 = blockIdx.x * 64;
  const int wid = t >> 6, l = t & 63;
  const int col16 = l & 15, rr = (l >> 4) * 4;
  const int cb = (l >> 4) * 8;

  if (t < 64) {
    const int s = edges[2 * (e0 + t)];
    const int d = edges[2 * (e0 + t) + 1];
    sa0[t] = attidx[s] + 192;
    sa1[t] = attidx[d] + 256;
  }
  // stage diff A-frags
  for (int it = 0; it < 6; it++) {
    const int id = t + 256 * it;      // 1536 tasks: 64 rows x 24 col-groups
    const int r = id / 24, g24 = id % 24;
    const int e = e0 + r;
    const int s = edges[2 * e], d = edges[2 * e + 1];
    const u16x8 a = *(const u16x8*)&stbf[(size_t)s * DDIM + g24 * 8];
    const u16x8 b = *(const u16x8*)&stbf[(size_t)d * DDIM + g24 * 8];
    short v[8];
#pragma unroll
    for (int j = 0; j < 8; j++) v[j] = f2bf(bf2f(a[j]) - bf2f(b[j]));
    const int rt = r >> 4, ks = g24 >> 2, g = g24 & 3;
    *(bf16x8*)&pdiff[((rt * 6 + ks) * 64 + g * 16 + (r & 15)) * 8] = *(bf16x8*)v;
  }
  __syncthreads();

  // per-lane one-hot targets for row (l&15) of each row-tile
  int a0v[4], a1v[4];
#pragma unroll
  for (int rt = 0; rt < 4; rt++) {
    a0v[rt] = sa0[rt * 16 + (l & 15)];
    a1v[rt] = sa1[rt * 16 + (l & 15)];
  }

  const int w5 = wid * 5;

  // ---- L1: [64x320] @ [320x(192|128)] fused, ks-outer outer-product ----
  {
    f32x4 acc[5][4];
#pragma unroll
    for (int u = 0; u < 5; u++)
#pragma unroll
      for (int rt = 0; rt < 4; rt++) acc[u][rt] = bc4(0.0f);

    for (int ks = 0; ks < 10; ks++) {
      bf16x8 A[4];
      if (ks < 6) {
#pragma unroll
        for (int rt = 0; rt < 4; rt++)
          A[rt] = *(const bf16x8*)&pdiff[((rt * 6 + ks) * 64 + l) * 8];
      } else {
        const int kb = ks * 32 + cb;
#pragma unroll
        for (int rt = 0; rt < 4; rt++) {
          short v[8];
#pragma unroll
          for (int j = 0; j < 8; j++) {
            const int kg = kb + j;
            v[j] = (kg == a0v[rt] || kg == a1v[rt]) ? (short)0x3F80 : (short)0;
          }
          A[rt] = *(bf16x8*)v;
        }
      }
      bf16x8 B[5];
#pragma unroll
      for (int u = 0; u < 5; u++) {
        const int unit = w5 + u;
        const short* bp = (unit < 12)
            ? &pWm1[((ks * 12 + unit) * 64 + l) * 8]
            : &pWa1[((ks * 8 + (unit - 12)) * 64 + l) * 8];
        B[u] = *(const bf16x8*)bp;
      }
#pragma unroll
      for (int u = 0; u < 5; u++)
#pragma unroll
        for (int rt = 0; rt < 4; rt++)
          acc[u][rt] = __builtin_amdgcn_mfma_f32_16x16x32_bf16(A[rt], B[u], acc[u][rt], 0, 0, 0);
    }

    // bias + relu + relayout to phm/pha
#pragma unroll
    for (int u = 0; u < 5; u++) {
      const int unit = w5 + u;
      const int isMsg = (unit < 12);
      const int ct = isMsg ? unit : unit - 12;
      const int col = ct * 16 + col16;
      const float bb = isMsg ? bm1[col] : ba1[col];
      const int ksp = col >> 5, gp = (col & 31) >> 3, jp = col & 7;
#pragma unroll
      for (int rt = 0; rt < 4; rt++)
#pragma unroll
        for (int j = 0; j < 4; j++) {
          const short hv = f2bf(fmaxf(acc[u][rt][j] + bb, 0.0f));
          if (isMsg) phm[((rt * 6 + ksp) * 64 + gp * 16 + rr + j) * 8 + jp] = hv;
          else       pha[((rt * 4 + ksp) * 64 + gp * 16 + rr + j) * 8 + jp] = hv;
        }
    }
  }
  __syncthreads();

  // ---- L2: wave owns 3 of 12 output cts x 4 rts ----
  {
    const int w3 = wid * 3;
    f32x4 m[3][4], av[3][4];
#pragma unroll
    for (int c = 0; c < 3; c++) {
      const int col = (w3 + c) * 16 + col16;
      const f32x4 bm = bc4(bm2[col]), ba = bc4(ba2[col]);
#pragma unroll
      for (int rt = 0; rt < 4; rt++) { m[c][rt] = bm; av[c][rt] = ba; }
    }
    for (int ks = 0; ks < 6; ks++) {
      bf16x8 A[4];
#pragma unroll
      for (int rt = 0; rt < 4; rt++)
        A[rt] = *(const bf16x8*)&phm[((rt * 6 + ks) * 64 + l) * 8];
      bf16x8 B[3];
#pragma unroll
      for (int c = 0; c < 3; c++)
        B[c] = *(const bf16x8*)&pWm2[((ks * 12 + w3 + c) * 64 + l) * 8];
#pragma unroll
      for (int c = 0; c < 3; c++)
#pragma unroll
        for (int rt = 0; rt < 4; rt++)
          m[c][rt] = __builtin_amdgcn_mfma_f32_16x16x32_bf16(A[rt], B[c], m[c][rt], 0, 0, 0);
    }
    for (int ks = 0; ks < 4; ks++) {
      bf16x8 A[4];
#pragma unroll
      for (int rt = 0; rt < 4; rt++)
        A[rt] = *(const bf16x8*)&pha[((rt * 4 + ks) * 64 + l) * 8];
      bf16x8 B[3];
#pragma unroll
      for (int c = 0; c < 3; c++)
        B[c] = *(const bf16x8*)&pWa2[((ks * 12 + w3 + c) * 64 + l) * 8];
#pragma unroll
      for (int c = 0; c < 3; c++)
#pragma unroll
        for (int rt = 0; rt < 4; rt++)
          av[c][rt] = __builtin_amdgcn_mfma_f32_16x16x32_bf16(A[rt], B[c], av[c][rt], 0, 0, 0);
    }

    // write combined values to LDS msgrow (overlays pdiff; dead since L1 + barrier)
    short* msgrow = pdiff;
#pragma unroll
    for (int c = 0; c < 3; c++) {
      const int col = (w3 + c) * 16 + col16;
#pragma unroll
      for (int rt = 0; rt < 4; rt++)
#pragma unroll
        for (int j = 0; j < 4; j++)
          msgrow[(rt * 16 + rr + j) * DDIM + col] = f2bf(m[c][rt][j] * sigm(av[c][rt][j]));
    }
  }
  __syncthreads();

  // coalesced copy msgrow -> msgbuf (64 rows x 384B)
  {
    const short* msgrow = pdiff;
    for (int it = 0; it < 6; it++) {
      const int id = t + 256 * it;      // 1536 tasks
      const int r = id / 24, g = id % 24;
      *(float4*)&msgbuf[(size_t)(e0 + r) * DDIM + g * 8] =
          *(const float4*)&msgrow[r * DDIM + g * 8];
    }
  }
}

// ---------------- MFMA GRU: 64 nodes/block, 256 threads (4 waves), zero LDS.
__global__ __launch_bounds__(256, 2) void k_gru_mfma(
    unsigned short* __restrict__ stbf,
    const unsigned short* __restrict__ msgbuf,
    const int* __restrict__ rowptr, const int* __restrict__ eidx,
    const short* __restrict__ pWih, const float* __restrict__ bih,
    const short* __restrict__ pWhh, const float* __restrict__ bhh) {
  const int t = threadIdx.x;
  const int n0 = blockIdx.x * 64;
  const int wid = t >> 6, l = t & 63;
  const int col16 = l & 15, rr = (l >> 4) * 4;
  const int cb = (l >> 4) * 8;
  const int row = n0 + wid * 16 + (l & 15);

  float afacc[6][8];
#pragma unroll
  for (int ks = 0; ks < 6; ks++)
#pragma unroll
    for (int j = 0; j < 8; j++) afacc[ks][j] = 0.0f;

  const int rbeg = rowptr[row], rend = rowptr[row + 1];
  for (int p = rbeg; p < rend; p++) {
    const int e = eidx[p];
    const unsigned short* mr = &msgbuf[(size_t)e * DDIM + cb];
#pragma unroll
    for (int ks = 0; ks < 6; ks++) {
      const u16x8 cc = *(const u16x8*)(mr + ks * 32);
#pragma unroll
      for (int j = 0; j < 8; j++) afacc[ks][j] += bf2f(cc[j]);
    }
  }

  bf16x8 af[6], sf[6];
#pragma unroll
  for (int ks = 0; ks < 6; ks++) {
    short v[8];
#pragma unroll
    for (int j = 0; j < 8; j++) v[j] = f2bf(afacc[ks][j]);
    af[ks] = *(bf16x8*)v;
    sf[ks] = *(const bf16x8*)&stbf[(size_t)row * DDIM + ks * 32 + cb];
  }

  for (int ct = 0; ct < 12; ct++) {
    const int c = ct * 16 + col16;
    f32x4 ir = bc4(bih[c]), iz = bc4(bih[c + DDIM]), in_ = bc4(bih[c + 2 * DDIM]);
    f32x4 hr = bc4(bhh[c]), hz = bc4(bhh[c + DDIM]), hn = bc4(bhh[c + 2 * DDIM]);
#pragma unroll
    for (int ks = 0; ks < 6; ks++) {
      const bf16x8 wr = *(const bf16x8*)&pWih[((size_t)(ks * 36 + ct) * 64 + l) * 8];
      const bf16x8 wz = *(const bf16x8*)&pWih[((size_t)(ks * 36 + ct + 12) * 64 + l) * 8];
      const bf16x8 wn = *(const bf16x8*)&pWih[((size_t)(ks * 36 + ct + 24) * 64 + l) * 8];
      ir  = __builtin_amdgcn_mfma_f32_16x16x32_bf16(af[ks], wr, ir, 0, 0, 0);
      iz  = __builtin_amdgcn_mfma_f32_16x16x32_bf16(af[ks], wz, iz, 0, 0, 0);
      in_ = __builtin_amdgcn_mfma_f32_16x16x32_bf16(af[ks], wn, in_, 0, 0, 0);
      const bf16x8 vr = *(const bf16x8*)&pWhh[((size_t)(ks * 36 + ct) * 64 + l) * 8];
      const bf16x8 vz = *(const bf16x8*)&pWhh[((size_t)(ks * 36 + ct + 12) * 64 + l) * 8];
      const bf16x8 vn = *(const bf16x8*)&pWhh[((size_t)(ks * 36 + ct + 24) * 64 + l) * 8];
      hr = __builtin_amdgcn_mfma_f32_16x16x32_bf16(sf[ks], vr, hr, 0, 0, 0);
      hz = __builtin_amdgcn_mfma_f32_16x16x32_bf16(sf[ks], vz, hz, 0, 0, 0);
      hn = __builtin_amdgcn_mfma_f32_16x16x32_bf16(sf[ks], vn, hn, 0, 0, 0);
    }
#pragma unroll
    for (int j = 0; j < 4; j++) {
      const size_t idx = (size_t)(n0 + wid * 16 + rr + j) * DDIM + c;
      const float sv = bf2f(stbf[idx]);
      const float r = sigm(ir[j] + hr[j]);
      const float z = sigm(iz[j] + hz[j]);
      const float nn = tanhf_(in_[j] + r * hn[j]);
      stbf[idx] = (unsigned short)f2bf((1.0f - z) * nn + z * sv);
    }
  }
}

// ---------------- MFMA head v3 + swizzle: 64 rows/block, 512 threads (8 waves).
__global__ __launch_bounds__(512, 4) void k_head_mfma(
    const unsigned short* __restrict__ stbf, const int* __restrict__ nig,
    const float* __restrict__ label, const int* __restrict__ subidx,
    const short* __restrict__ pWt1, const float* __restrict__ bt1,
    const short* __restrict__ pWt2, const float* __restrict__ bt2,
    const short* __restrict__ pWt3, const float* __restrict__ bt3,
    const short* __restrict__ pWa1, const float* __restrict__ ba1,
    const short* __restrict__ pWa2, const float* __restrict__ ba2,
    const short* __restrict__ pWa3, const float* __restrict__ ba3,
    float* __restrict__ REP) {
  __shared__ short u1[16384];    // pd [rt<4][ks<6][64][8] (24KB) / ph2 t+a (16+16KB)
  __shared__ short ph1[16384];   // ph1t + ph1a, each [rt<4][ks<4][64][8]
  __shared__ float la[64 * KMIX];
  __shared__ int   ssub[64];
  __shared__ float slab[64];
  __shared__ float lse[64];

  const int t = threadIdx.x;
  const int r0 = blockIdx.x * 64;
  float* rep = REP + (size_t)(blockIdx.x & (NREP - 1)) * REP_STRIDE;

  if (t < 64) {
    const int gr = r0 + t;
    const int sb = (gr < NEOUT) ? subidx[gr] : 0;
    ssub[t] = sb;
    slab[t] = (gr < NEOUT) ? label[gr] : 0.0f;
    if (gr < NEOUT) atomicAdd(&rep[CNT_OFF + sb], 1.0f);
  }

  // stage diff A-frags into pd (u1), swizzled
  for (int it = 0; it < 3; it++) {
    const int id = t + 512 * it;      // 1536 tasks: 64 rows x 24 col-groups
    const int r = id / 24, g24 = id % 24;
    const int gr = r0 + r;
    const int ok = (gr < NEOUT);
    const int ia = ok ? nig[2 * gr] : 0;
    const int ib = ok ? nig[2 * gr + 1] : 0;   // ia==ib -> zero diff on pad rows
    const u16x8 a = *(const u16x8*)&stbf[(size_t)ia * DDIM + g24 * 8];
    const u16x8 b = *(const u16x8*)&stbf[(size_t)ib * DDIM + g24 * 8];
    short v[8];
#pragma unroll
    for (int j = 0; j < 8; j++) v[j] = f2bf(bf2f(a[j]) - bf2f(b[j]));
    const int rt = r >> 4, ks = g24 >> 2, g = g24 & 3;
    *(bf16x8*)&u1[swz((rt * 6 + ks) * 64 + g * 16 + (r & 15)) * 8] = *(bf16x8*)v;
  }
  __syncthreads();

  const int wid = t >> 6, l = t & 63;
  const int b = wid >> 2, cw = wid & 3;
  const int col16 = l & 15, rr = (l >> 4) * 4;

  const short* pW1 = b ? pWa1 : pWt1;
  const short* pW2 = b ? pWa2 : pWt2;
  const short* pW3 = b ? pWa3 : pWt3;
  const float* bv1 = b ? ba1 : bt1;
  const float* bv2 = b ? ba2 : bt2;
  const float* bv3 = b ? ba3 : bt3;
  short* ph1b = ph1 + b * 8192;
  short* ph2b = u1 + b * 8192;

  // ---- L1: K=192, this wave's 2 cts; B persistent in regs ----
  {
    bf16x8 B1[12];
    float bias[2];
#pragma unroll
    for (int c2 = 0; c2 < 2; c2++) {
      const int ct = cw * 2 + c2;
      bias[c2] = bv1[ct * 16 + col16];
#pragma unroll
      for (int ks = 0; ks < 6; ks++)
        B1[c2 * 6 + ks] = *(const bf16x8*)&pW1[((ks * 8 + ct) * 64 + l) * 8];
    }
    for (int rt = 0; rt < 4; rt++) {
      bf16x8 a[6];
#pragma unroll
      for (int ks = 0; ks < 6; ks++)
        a[ks] = *(const bf16x8*)&u1[swz((rt * 6 + ks) * 64 + l) * 8];
      f32x4 acc0 = bc4(bias[0]), acc1 = bc4(bias[1]);
#pragma unroll
      for (int ks = 0; ks < 6; ks++) {
        acc0 = __builtin_amdgcn_mfma_f32_16x16x32_bf16(a[ks], B1[ks], acc0, 0, 0, 0);
        acc1 = __builtin_amdgcn_mfma_f32_16x16x32_bf16(a[ks], B1[6 + ks], acc1, 0, 0, 0);
      }
#pragma unroll
      for (int c2 = 0; c2 < 2; c2++) {
        const int col = (cw * 2 + c2) * 16 + col16;
        const int ksp = col >> 5, gp = (col & 31) >> 3, jp = col & 7;
        const f32x4 acc = c2 ? acc1 : acc0;
#pragma unroll
        for (int j = 0; j < 4; j++)
          ph1b[swz((rt * 4 + ksp) * 64 + gp * 16 + rr + j) * 8 + jp] = f2bf(fmaxf(acc[j], 0.0f));
      }
    }
  }
  __syncthreads();   // pd dead; ph1 complete

  // ---- L2: K=128 ----
  {
    bf16x8 B2[8];
    float bias[2];
#pragma unroll
    for (int c2 = 0; c2 < 2; c2++) {
      const int ct = cw * 2 + c2;
      bias[c2] = bv2[ct * 16 + col16];
#pragma unroll
      for (int ks = 0; ks < 4; ks++)
        B2[c2 * 4 + ks] = *(const bf16x8*)&pW2[((ks * 8 + ct) * 64 + l) * 8];
    }
    for (int rt = 0; rt < 4; rt++) {
      bf16x8 a[4];
#pragma unroll
      for (int ks = 0; ks < 4; ks++)
        a[ks] = *(const bf16x8*)&ph1b[swz((rt * 4 + ks) * 64 + l) * 8];
      f32x4 acc0 = bc4(bias[0]), acc1 = bc4(bias[1]);
#pragma unroll
      for (int ks = 0; ks < 4; ks++) {
        acc0 = __builtin_amdgcn_mfma_f32_16x16x32_bf16(a[ks], B2[ks], acc0, 0, 0, 0);
        acc1 = __builtin_amdgcn_mfma_f32_16x16x32_bf16(a[ks], B2[4 + ks], acc1, 0, 0, 0);
      }
#pragma unroll
      for (int c2 = 0; c2 < 2; c2++) {
        const int col = (cw * 2 + c2) * 16 + col16;
        const int ksp = col >> 5, gp = (col & 31) >> 3, jp = col & 7;
        const f32x4 acc = c2 ? acc1 : acc0;
#pragma unroll
        for (int j = 0; j < 4; j++)
          ph2b[swz((rt * 4 + ksp) * 64 + gp * 16 + rr + j) * 8 + jp] = f2bf(fmaxf(acc[j], 0.0f));
      }
    }
  }
  __syncthreads();

  // ---- L3: K=128, N=32 (cols>=20 zero-padded) ----
  {
    const int ct3 = cw & 1, rth = cw >> 1;
    const int col = ct3 * 16 + col16;
    bf16x8 B3[4];
#pragma unroll
    for (int ks = 0; ks < 4; ks++)
      B3[ks] = *(const bf16x8*)&pW3[((ks * 2 + ct3) * 64 + l) * 8];
    const float bias = (col < KMIX) ? bv3[col] : 0.0f;
#pragma unroll
    for (int i = 0; i < 2; i++) {
      const int rt = rth * 2 + i;
      bf16x8 a[4];
#pragma unroll
      for (int ks = 0; ks < 4; ks++)
        a[ks] = *(const bf16x8*)&ph2b[swz((rt * 4 + ks) * 64 + l) * 8];
      f32x4 acc = bc4(bias);
#pragma unroll
      for (int ks = 0; ks < 4; ks++)
        acc = __builtin_amdgcn_mfma_f32_16x16x32_bf16(a[ks], B3[ks], acc, 0, 0, 0);
      if (col < KMIX) {
        if (b == 0) {
#pragma unroll
          for (int j = 0; j < 4; j++) {
            const int r = rt * 16 + rr + j;
            if (r0 + r < NEOUT) {
              const float lt = acc[j];
              const float adj = fmaxf(lt, 0.0f) + logf(1.0f + __expf(-fabsf(lt))) - lt * slab[r];
              atomicAdd(&rep[LOSS_OFF + ssub[r] * KMIX + col], adj);
            }
          }
        } else {
#pragma unroll
          for (int j = 0; j < 4; j++)
            la[(rt * 16 + rr + j) * KMIX + col] = acc[j];
        }
      }
    }
  }
  __syncthreads();
  if (t < 64) {
    float m = -1e30f;
    for (int k = 0; k < KMIX; k++) m = fmaxf(m, la[t * KMIX + k]);
    float s = 0.0f;
    for (int k = 0; k < KMIX; k++) s += __expf(la[t * KMIX + k] - m);
    lse[t] = m + logf(s);
  }
  __syncthreads();
  {
    const int r = t >> 3;
    if (r0 + r < NEOUT) {
#pragma unroll
      for (int i = 0; i < 3; i++) {
        const int c = (t & 7) + 8 * i;
        if (c < KMIX)
          atomicAdd(&rep[ALPHA_OFF + ssub[r] * KMIX + c], la[r * KMIX + c] - lse[r]);
      }
    }
  }
}

// ---------------- fold 64 replicas into final arrays (coalesced)
__global__ __launch_bounds__(256) void k_red(const float* __restrict__ REP,
                                             float* __restrict__ fin) {
  const int i = blockIdx.x * 256 + threadIdx.x;
  if (i < REP_STRIDE) {
    float s = 0.0f;
    for (int r = 0; r < NREP; r++) s += REP[(size_t)r * REP_STRIDE + i];
    fin[i] = s;
  }
}

// ---------------- final: per-subgraph logsumexp, reduce to scalar
__global__ __launch_bounds__(1024) void k_final(
    const float* __restrict__ fin, float* __restrict__ out) {
  __shared__ float part[1024];
  const int s = threadIdx.x;
  const float* red_loss  = fin + LOSS_OFF;
  const float* red_alpha = fin + ALPHA_OFF;
  const float c = fmaxf(fin[CNT_OFF + s], 1.0f);
  float v[KMIX];
  float m = -1e30f;
  for (int k = 0; k < KMIX; k++) {
    v[k] = -red_loss[s * KMIX + k] + red_alpha[s * KMIX + k] / c;
    m = fmaxf(m, v[k]);
  }
  float sum = 0.0f;
  for (int k = 0; k < KMIX; k++) sum += __expf(v[k] - m);
  part[s] = m + logf(sum);
  __syncthreads();
  for (int st = 512; st > 0; st >>= 1) {
    if (s < st) part[s] += part[s + st];
    __syncthreads();
  }
  if (s == 0) out[0] = -part[0] / (float)NEOUT;
}

extern "C" void kernel_launch(void* const* d_in, const int* in_sizes, int n_in,
                              void* d_out, int out_size, void* d_ws, size_t ws_size,
                              hipStream_t stream) {
  const float* A      = (const float*)d_in[0];
  const int*   edges  = (const int*)d_in[1];
  const int*   attidx = (const int*)d_in[2];
  const int*   nif    = (const int*)d_in[3];
  const int*   cl     = (const int*)d_in[4];
  const int*   nig    = (const int*)d_in[5];
  const float* label  = (const float*)d_in[6];
  const int*   subidx = (const int*)d_in[7];
  const float* Wdec   = (const float*)d_in[8];
  const float* bdec   = (const float*)d_in[9];
  const float* cemb   = (const float*)d_in[10];
  const float* Wm1    = (const float*)d_in[11];
  const float* bm1    = (const float*)d_in[12];
  const float* Wm2    = (const float*)d_in[13];
  const float* bm2    = (const float*)d_in[14];
  const float* Wa1    = (const float*)d_in[15];
  const float* ba1    = (const float*)d_in[16];
  const float* Wa2    = (const float*)d_in[17];
  const float* ba2    = (const float*)d_in[18];
  const float* Wih    = (const float*)d_in[19];
  const float* bih    = (const float*)d_in[20];
  const float* Whh    = (const float*)d_in[21];
  const float* bhh    = (const float*)d_in[22];
  const float* Wt1    = (const float*)d_in[23];
  const float* bt1    = (const float*)d_in[24];
  const float* Wt2    = (const float*)d_in[25];
  const float* bt2    = (const float*)d_in[26];
  const float* Wt3    = (const float*)d_in[27];
  const float* bt3    = (const float*)d_in[28];
  const float* Wha1   = (const float*)d_in[29];
  const float* hba1   = (const float*)d_in[30];
  const float* Wha2   = (const float*)d_in[31];
  const float* hba2   = (const float*)d_in[32];
  const float* Wha3   = (const float*)d_in[33];
  const float* hba3   = (const float*)d_in[34];

  char* ws = (char*)d_ws;
  const size_t SZ_STBF = (size_t)NGNN * DDIM * sizeof(short);     // 12,582,912
  const size_t SZ_MSG  = (size_t)NEDGE * DDIM * sizeof(short);    // 76,800,000
  const size_t SZ_REP  = (size_t)NREP * REP_STRIDE * sizeof(float); // 10.75 MB

  unsigned short* stbf   = (unsigned short*)ws;
  unsigned short* msgbuf = (unsigned short*)(ws + SZ_STBF);
  // overlays inside the msgbuf region (disjoint lifetimes, stream-ordered):
  float* nf  = (float*)(ws + SZ_STBF);            // dec output, dead before edge
  float* REP = (float*)(ws + SZ_STBF);            // used only after last gru
  float* fin = (float*)(ws + SZ_STBF + SZ_REP);

  char* tail = ws + SZ_STBF + SZ_MSG;
  int* rowptr = (int*)tail;                       // (NGNN+1) ints, pad to 131,328
  int* degcur = (int*)(tail + 131328);            // NGNN ints (deg, then cursor)
  int* eidx   = (int*)(tail + 131328 + 131072);   // NEDGE ints = 800,000 B
  short* pk   = (short*)(tail + 131328 + 131072 + 800000);
  short* pWm1  = pk;             // K=320: 10*12*512
  short* pWa1e = pWm1  + 61440;  // K=320: 10*8*512
  short* pWm2  = pWa1e + 40960;  // 6*12*512
  short* pWa2e = pWm2  + 36864;  // 4*12*512
  short* pWt1  = pWa2e + 24576;  // 6*8*512
  short* pWt2  = pWt1  + 24576;  // 4*8*512
  short* pWt3  = pWt2  + 16384;  // 4*2*512
  short* pWh1  = pWt3  + 4096;   // 6*8*512
  short* pWh2  = pWh1  + 24576;  // 4*8*512
  short* pWh3  = pWh2  + 16384;  // 4*2*512
  short* pWih  = pWh3  + 4096;   // 6*36*512
  short* pWhh  = pWih  + 110592; // 6*36*512

  // merged pack (all 12 weights) + degcur zeroing in one launch
  PackArgs pa;
  const float* srcs[12] = {Wm1, Wa1, Wm2, Wa2, Wt1, Wt2, Wt3, Wha1, Wha2, Wha3, Wih, Whh};
  short* dsts[12] = {pWm1, pWa1e, pWm2, pWa2e, pWt1, pWt2, pWt3, pWh1, pWh2, pWh3, pWih, pWhh};
  const int Ns[12]  = {192, 128, 192, 192, 128, 128, 20, 128, 128, 20, 576, 576};
  const int CTs[12] = {12, 8, 12, 12, 8, 8, 2, 8, 8, 2, 36, 36};
  const int KSs[12] = {10, 10, 6, 4, 6, 4, 4, 6, 4, 4, 6, 6};
  int acc = 0;
  for (int m = 0; m < 12; m++) {
    pa.W[m] = srcs[m]; pa.out[m] = dsts[m]; pa.N[m] = Ns[m]; pa.CT[m] = CTs[m];
    pa.start[m] = acc;
    acc += KSs[m] * CTs[m];
  }
  pa.start[12] = acc;            // 928 pack blocks
  pa.deg = degcur;
  k_pack_all<<<acc + 64, 64, 0, stream>>>(pa);   // +64 zeroing blocks

  // CSR build by dst (once; edges are constant across props)
  k_hist<<<(NEDGE + 255) / 256, 256, 0, stream>>>(edges, degcur);
  k_scan<<<1, 1024, 0, stream>>>(degcur, rowptr, degcur);
  k_scatter<<<(NEDGE + 255) / 256, 256, 0, stream>>>(edges, degcur, eidx);

  k_dec<<<NGNN, 128, 0, stream>>>(A, Wdec, bdec, nf);
  k_state<<<NGNN, 192, 0, stream>>>(nf, cemb, nif, cl, stbf);
  for (int p = 0; p < 2; p++) {
    k_edge_mfma<<<NEDGE / 64, 256, 0, stream>>>(stbf, edges, attidx,
        bm1, pWm1, pWm2, bm2, ba1, pWa1e, pWa2e, ba2, msgbuf);
    k_gru_mfma<<<NGNN / 64, 256, 0, stream>>>(stbf, msgbuf, rowptr, eidx,
        pWih, bih, pWhh, bhh);
  }
  hipMemsetAsync(REP, 0, SZ_REP, stream);
  k_head_mfma<<<(NEOUT + 63) / 64, 512, 0, stream>>>(stbf, nig, label, subidx,
      pWt1, bt1, pWt2, bt2, pWt3, bt3, pWh1, hba1, pWh2, hba2, pWh3, hba3, REP);
  k_red<<<(REP_STRIDE + 255) / 256, 256, 0, stream>>>(REP, fin);
  k_final<<<1, 1024, 0, stream>>>(fin, (float*)d_out);
}